// Round 1
// baseline (27959.509 us; speedup 1.0000x reference)
//
#include <hip/hip_runtime.h>

#define KEPS 1e-4f

// ---------------- static device workspace (allocated at module load) ----------------
__device__ float g_z0[2u*512*8*2048];     // layer0 input-proj Z [dir][t][b][4H]
__device__ float g_z1[2u*512*8*2048];
__device__ float g_x1[8u*512*1024];       // BiLSTM layer0 output [B,T,2H]
__device__ float g_hres[8u*512*1024];     // residual stream [B,T,D]
__device__ float g_y[8u*512*1024];        // LN output / scratch
__device__ float g_qlin[8u*8*512*128];    // [B,H,T,DH]
__device__ float g_klin[8u*8*512*128];
__device__ float g_vlin[8u*8*512*128];
__device__ float g_qp[8u*8*512*256];      // q' [B,H,T,M]
__device__ float g_ddb[8u*8*512*256];     // dd scratch for k
__device__ float g_kT[8u*8*256*512];      // k'^T [B,H,M,T]
__device__ float g_ctx[64u*256*128];      // [BH,M,DH]
__device__ float g_obuf[8u*512*1024];     // merged attention out [B,T,D]
__device__ float g_ffb[8u*512*4096];      // FF hidden [B*T,FF]
__device__ float g_bs0[2*2048];
__device__ float g_bs1[2*2048];
__device__ float g_projs[256*128];        // proj * dn
__device__ float g_diagq[32768];
__device__ float g_diagk[32768];
__device__ float g_kmx[64];
__device__ float g_ksum[64*256];
__device__ float g_dinv[32768];
__device__ float g_hcur[2*2*8*512];       // [buf][dir][b][H]
__device__ float g_pooled[8*1024];
__device__ int   g_bars[64];              // software barrier counters

// ---------------- helpers ----------------
__device__ __forceinline__ float gelu_f(float x) {
  return 0.5f * x * (1.f + erff(x * 0.70710678118654752f));
}
__device__ __forceinline__ float gload(const float* p) {
  return __hip_atomic_load(p, __ATOMIC_RELAXED, __HIP_MEMORY_SCOPE_AGENT);
}
__device__ __forceinline__ void gstore(float* p, float v) {
  __hip_atomic_store(p, v, __ATOMIC_RELAXED, __HIP_MEMORY_SCOPE_AGENT);
}
// global barrier over 128 workgroups (one direction), monotonic counter
__device__ __forceinline__ void gbar(int* bar, int phase) {
  __syncthreads();
  if (threadIdx.x == 0) {
    __threadfence();
    __hip_atomic_fetch_add(bar, 1, __ATOMIC_RELEASE, __HIP_MEMORY_SCOPE_AGENT);
    const int need = 128 * phase;
    while (__hip_atomic_load(bar, __ATOMIC_ACQUIRE, __HIP_MEMORY_SCOPE_AGENT) < need)
      __builtin_amdgcn_s_sleep(2);
  }
  __syncthreads();
}

__global__ void k_zero(int* p) { p[threadIdx.x] = 0; }

__global__ void k_add2(float* __restrict__ dst, const float* __restrict__ a,
                       const float* __restrict__ b, int n) {
  int i = blockIdx.x * 256 + threadIdx.x;
  if (i < n) dst[i] = a[i] + b[i];
}
__global__ void k_scale(float* __restrict__ dst, const float* __restrict__ a,
                        float s, int n) {
  int i = blockIdx.x * 256 + threadIdx.x;
  if (i < n) dst[i] = a[i] * s;
}

// ---------------- generic tiled fp32 GEMM ----------------
// C[M,N] = A[M,K] @ (BT ? W[N,K]^T : B[K,N]) + bias[N]
// MODE: 0 plain, 1 LSTM-Z store [dir][t][b][4H], 2 heads store [B,H,T,DH],
//       3 add-into-C (residual), 4 GELU, 5 o-store (dinv scale + head merge)
template<int BT, int MODE>
__global__ __launch_bounds__(256)
void k_gemm(const float* __restrict__ A, const float* __restrict__ Bw,
            const float* __restrict__ bias, float* __restrict__ C,
            int Mdim, int Ndim, int Kdim,
            long long aBS, long long bBS, long long cBS, long long biasBS,
            const float* __restrict__ aux)
{
  __shared__ float As[16][128];
  __shared__ float Bs[16][128];
  const int tid = threadIdx.x;
  const int tx = tid & 15, ty = tid >> 4;
  const int m0 = blockIdx.y * 128, n0 = blockIdx.x * 128;
  const int z = blockIdx.z;
  const float* Ab = A + (long long)z * aBS;
  const float* Bb = Bw + (long long)z * bBS;
  float acc[8][8] = {};

  for (int k0 = 0; k0 < Kdim; k0 += 16) {
    #pragma unroll
    for (int l0 = 0; l0 < 512; l0 += 256) {
      const int l = l0 + tid;
      const int r = l >> 2, kq = (l & 3) * 4;
      float4 v = *(const float4*)&Ab[(long long)(m0 + r) * Kdim + k0 + kq];
      As[kq+0][r] = v.x; As[kq+1][r] = v.y; As[kq+2][r] = v.z; As[kq+3][r] = v.w;
    }
    if (BT) {
      #pragma unroll
      for (int l0 = 0; l0 < 512; l0 += 256) {
        const int l = l0 + tid;
        const int r = l >> 2, kq = (l & 3) * 4;
        float4 v = *(const float4*)&Bb[(long long)(n0 + r) * Kdim + k0 + kq];
        Bs[kq+0][r] = v.x; Bs[kq+1][r] = v.y; Bs[kq+2][r] = v.z; Bs[kq+3][r] = v.w;
      }
    } else {
      #pragma unroll
      for (int l0 = 0; l0 < 512; l0 += 256) {
        const int l = l0 + tid;
        const int kr = l >> 5, n4 = (l & 31) * 4;
        *(float4*)&Bs[kr][n4] = *(const float4*)&Bb[(long long)(k0 + kr) * Ndim + n0 + n4];
      }
    }
    __syncthreads();
    #pragma unroll
    for (int kk = 0; kk < 16; ++kk) {
      float4 af0 = *(const float4*)&As[kk][ty*4];
      float4 af1 = *(const float4*)&As[kk][64 + ty*4];
      float4 bf0 = *(const float4*)&Bs[kk][tx*4];
      float4 bf1 = *(const float4*)&Bs[kk][64 + tx*4];
      float av[8] = {af0.x,af0.y,af0.z,af0.w,af1.x,af1.y,af1.z,af1.w};
      float bv[8] = {bf0.x,bf0.y,bf0.z,bf0.w,bf1.x,bf1.y,bf1.z,bf1.w};
      #pragma unroll
      for (int i = 0; i < 8; ++i)
        #pragma unroll
        for (int j = 0; j < 8; ++j)
          acc[i][j] = fmaf(av[i], bv[j], acc[i][j]);
    }
    __syncthreads();
  }

  float bias0[4] = {0.f,0.f,0.f,0.f}, bias1[4] = {0.f,0.f,0.f,0.f};
  if (MODE != 5 && bias != nullptr) {
    const float* bz = bias + (long long)z * biasBS;
    float4 t0 = *(const float4*)&bz[n0 + tx*4];
    float4 t1 = *(const float4*)&bz[n0 + 64 + tx*4];
    bias0[0]=t0.x; bias0[1]=t0.y; bias0[2]=t0.z; bias0[3]=t0.w;
    bias1[0]=t1.x; bias1[1]=t1.y; bias1[2]=t1.z; bias1[3]=t1.w;
  }
  float* Cz = C + (long long)z * cBS;
  #pragma unroll
  for (int i = 0; i < 8; ++i) {
    const int m = m0 + ((i < 4) ? (ty*4 + i) : (64 + ty*4 + (i - 4)));
    #pragma unroll
    for (int jb = 0; jb < 2; ++jb) {
      const int ci = n0 + (jb ? 64 : 0) + tx*4;
      float4 v;
      v.x = acc[i][jb*4+0] + (jb ? bias1[0] : bias0[0]);
      v.y = acc[i][jb*4+1] + (jb ? bias1[1] : bias0[1]);
      v.z = acc[i][jb*4+2] + (jb ? bias1[2] : bias0[2]);
      v.w = acc[i][jb*4+3] + (jb ? bias1[3] : bias0[3]);
      if (MODE == 4) { v.x = gelu_f(v.x); v.y = gelu_f(v.y); v.z = gelu_f(v.z); v.w = gelu_f(v.w); }
      if (MODE == 0 || MODE == 4) {
        *(float4*)&Cz[(long long)m * Ndim + ci] = v;
      } else if (MODE == 3) {
        float4 o4 = *(const float4*)&Cz[(long long)m * Ndim + ci];
        v.x += o4.x; v.y += o4.y; v.z += o4.z; v.w += o4.w;
        *(float4*)&Cz[(long long)m * Ndim + ci] = v;
      } else if (MODE == 1) {
        const int b_ = m >> 9, t_ = m & 511;
        *(float4*)&Cz[((long long)(t_*8 + b_))*2048 + ci] = v;
      } else if (MODE == 2) {
        const int b_ = m >> 9, t_ = m & 511;
        const int hd = ci >> 7;
        *(float4*)&Cz[(((long long)(b_*8 + hd))*512 + t_)*128 + (ci & 127)] = v;
      } else if (MODE == 5) {
        const int b_ = z >> 3, hd = z & 7;
        const float sc = aux[(long long)z*512 + m];
        v.x *= sc; v.y *= sc; v.z *= sc; v.w *= sc;
        *(float4*)&Cz[((long long)(b_*512 + m))*1024 + hd*128 + ci] = v;
      }
    }
  }
}

// ---------------- persistent BiLSTM recurrence ----------------
// grid = 256 WGs: WGs [0,128) = fwd, [128,256) = bwd. Each WG owns 4 hidden units.
__global__ __launch_bounds__(256)
void k_lstm(const float* __restrict__ Z, const float* __restrict__ Whh,
            float* __restrict__ outh, float* __restrict__ hcur, int* __restrict__ barBase)
{
  const int wg = blockIdx.x & 127, dir = blockIdx.x >> 7;
  const int tid = threadIdx.x;
  int* bar = barBase + dir * 16;
  __shared__ float Wl[16][512];   // 16 gate rows x H
  __shared__ float hl[8][512];    // staged h for all batches
  __shared__ float dots[16][8];
  const float* Wd = Whh + (long long)dir * 2048 * 512;
  const int u0 = wg * 4;
  for (int idx = tid; idx < 16*512; idx += 256) {
    const int r = idx >> 9, k = idx & 511;
    const int grow = (r >> 2) * 512 + u0 + (r & 3); // gate g=r>>2, unit j=r&3
    Wl[r][k] = Wd[(long long)grow * 512 + k];
  }
  if (tid < 32) {
    const int j = tid >> 3, b = tid & 7;
    gstore(&hcur[(long long)(0*2 + dir)*4096 + b*512 + u0 + j], 0.f);
  }
  float cst = 0.f; // cell state for threads tid<32 (unit j=tid>>3, batch b=tid&7)
  gbar(bar, 1);
  for (int s = 0; s < 512; ++s) {
    const int t = dir ? (511 - s) : s;
    const float* hsrc = hcur + (long long)((s & 1)*2 + dir) * 4096;
    for (int idx = tid; idx < 4096; idx += 256)
      (&hl[0][0])[idx] = gload(&hsrc[idx]);
    __syncthreads();
    const int l = tid & 63;
    const int b0 = (tid >> 6) * 2, rg = ((l >> 4) & 3) * 4, ks = l & 15;
    float acc[2][4] = {{0,0,0,0},{0,0,0,0}};
    #pragma unroll
    for (int kc = 0; kc < 8; ++kc) {
      const int kof = ks*32 + (((kc + ks) & 7) << 2);  // bank-rotated
      float4 ha = *(const float4*)&hl[b0][kof];
      float4 hb = *(const float4*)&hl[b0+1][kof];
      #pragma unroll
      for (int rr = 0; rr < 4; ++rr) {
        float4 w = *(const float4*)&Wl[rg+rr][kof];
        acc[0][rr] += w.x*ha.x + w.y*ha.y + w.z*ha.z + w.w*ha.w;
        acc[1][rr] += w.x*hb.x + w.y*hb.y + w.z*hb.z + w.w*hb.w;
      }
    }
    #pragma unroll
    for (int off = 1; off < 16; off <<= 1) {
      #pragma unroll
      for (int rr = 0; rr < 4; ++rr) {
        acc[0][rr] += __shfl_xor(acc[0][rr], off, 64);
        acc[1][rr] += __shfl_xor(acc[1][rr], off, 64);
      }
    }
    if (ks == 0) {
      #pragma unroll
      for (int rr = 0; rr < 4; ++rr) {
        dots[rg+rr][b0]   = acc[0][rr];
        dots[rg+rr][b0+1] = acc[1][rr];
      }
    }
    __syncthreads();
    if (tid < 32) {
      const int j = tid >> 3, b = tid & 7;
      const float* zp = Z + (((long long)dir*512 + t)*8 + b)*2048 + u0 + j;
      const float zi = dots[j][b]    + zp[0];
      const float zf = dots[4+j][b]  + zp[512];
      const float zg = dots[8+j][b]  + zp[1024];
      const float zo = dots[12+j][b] + zp[1536];
      const float ig = 1.f/(1.f+expf(-zi));
      const float fg = 1.f/(1.f+expf(-zf));
      const float og = 1.f/(1.f+expf(-zo));
      cst = fg*cst + ig*tanhf(zg);
      const float hv = og*tanhf(cst);
      gstore(&hcur[(long long)(((s+1)&1)*2 + dir)*4096 + b*512 + u0 + j], hv);
      outh[((long long)b*512 + t)*1024 + dir*512 + u0 + j] = hv;
    }
    gbar(bar, s + 2);
  }
}

// ---------------- LayerNorm (one row of 1024 per block) ----------------
__global__ __launch_bounds__(256)
void k_ln(const float* __restrict__ X, const float* __restrict__ gw,
          const float* __restrict__ bw, float* __restrict__ Y)
{
  const int row = blockIdx.x, tid = threadIdx.x;
  const float* xr = X + (long long)row * 1024;
  float4 v = *(const float4*)&xr[tid*4];
  float s  = v.x + v.y + v.z + v.w;
  float ss = v.x*v.x + v.y*v.y + v.z*v.z + v.w*v.w;
  #pragma unroll
  for (int off = 1; off < 64; off <<= 1) {
    s  += __shfl_xor(s, off, 64);
    ss += __shfl_xor(ss, off, 64);
  }
  __shared__ float rs[4], rss[4];
  const int w = tid >> 6;
  if ((tid & 63) == 0) { rs[w] = s; rss[w] = ss; }
  __syncthreads();
  s  = rs[0] + rs[1] + rs[2] + rs[3];
  ss = rss[0] + rss[1] + rss[2] + rss[3];
  const float mu = s * (1.f/1024.f);
  const float var = ss * (1.f/1024.f) - mu*mu;
  const float rstd = rsqrtf(var + 1e-5f);
  float4 g4 = *(const float4*)&gw[tid*4];
  float4 b4 = *(const float4*)&bw[tid*4];
  float4 o;
  o.x = (v.x - mu)*rstd*g4.x + b4.x;
  o.y = (v.y - mu)*rstd*g4.y + b4.y;
  o.z = (v.z - mu)*rstd*g4.z + b4.z;
  o.w = (v.w - mu)*rstd*g4.w + b4.w;
  *(float4*)&Y[(long long)row*1024 + tid*4] = o;
}

// ---------------- FAVOR helpers ----------------
__global__ void k_diag(const float* __restrict__ X, float* __restrict__ dout)
{
  const int tid = threadIdx.x;
  const int row = blockIdx.x*4 + (tid >> 6);
  const int lane = tid & 63;
  float2 v = *(const float2*)&X[(long long)row*128 + lane*2];
  float ss = v.x*v.x + v.y*v.y;
  #pragma unroll
  for (int off = 1; off < 64; off <<= 1) ss += __shfl_xor(ss, off, 64);
  if (lane == 0) dout[row] = ss * 0.044194173824159216f; // 0.5 * dn^2, dn=128^-0.25
}

__global__ void k_favq(float* __restrict__ dd, const float* __restrict__ diag)
{
  const int tid = threadIdx.x;
  const int row = blockIdx.x*4 + (tid >> 6);
  const int lane = tid & 63;
  float4 v = *(const float4*)&dd[(long long)row*256 + lane*4];
  float mx = fmaxf(fmaxf(v.x, v.y), fmaxf(v.z, v.w));
  #pragma unroll
  for (int off = 1; off < 64; off <<= 1) mx = fmaxf(mx, __shfl_xor(mx, off, 64));
  const float dg = diag[row];
  float4 o;
  o.x = (expf(v.x - dg - mx) + KEPS)*0.0625f;
  o.y = (expf(v.y - dg - mx) + KEPS)*0.0625f;
  o.z = (expf(v.z - dg - mx) + KEPS)*0.0625f;
  o.w = (expf(v.w - dg - mx) + KEPS)*0.0625f;
  *(float4*)&dd[(long long)row*256 + lane*4] = o;
}

__global__ __launch_bounds__(256)
void k_kmax(const float* __restrict__ dd, float* __restrict__ kmx)
{
  const int bh = blockIdx.x, tid = threadIdx.x;
  const float* p = dd + (long long)bh * 131072;
  float mx = -3.4e38f;
  for (int i = tid*4; i < 131072; i += 1024) {
    float4 v = *(const float4*)&p[i];
    mx = fmaxf(mx, fmaxf(fmaxf(v.x, v.y), fmaxf(v.z, v.w)));
  }
  #pragma unroll
  for (int off = 1; off < 64; off <<= 1) mx = fmaxf(mx, __shfl_xor(mx, off, 64));
  __shared__ float red[4];
  if ((tid & 63) == 0) red[tid >> 6] = mx;
  __syncthreads();
  if (tid == 0) kmx[bh] = fmaxf(fmaxf(red[0], red[1]), fmaxf(red[2], red[3]));
}

__global__ void k_fkT(const float* __restrict__ dd, const float* __restrict__ diag,
                      const float* __restrict__ kmx, float* __restrict__ kT)
{
  __shared__ float tile[32][33];
  const int bh = blockIdx.z;
  const int t0 = blockIdx.x * 32, m0 = blockIdx.y * 32;
  const int tx = threadIdx.x, ty = threadIdx.y;
  const float km = kmx[bh];
  #pragma unroll
  for (int j = 0; j < 4; ++j) {
    const int t = t0 + ty + j*8;
    const float v = dd[((long long)bh*512 + t)*256 + m0 + tx];
    tile[ty + j*8][tx] = (expf(v - diag[bh*512 + t] - km) + KEPS) * 0.0625f;
  }
  __syncthreads();
  #pragma unroll
  for (int j = 0; j < 4; ++j) {
    const int m = m0 + ty + j*8;
    kT[((long long)bh*256 + m)*512 + t0 + tx] = tile[tx][ty + j*8];
  }
}

__global__ void k_ksum(const float* __restrict__ kT, float* __restrict__ ksum)
{
  const int tid = threadIdx.x;
  const int row = blockIdx.x*4 + (tid >> 6);
  const int lane = tid & 63;
  float4 a = *(const float4*)&kT[(long long)row*512 + lane*8];
  float4 b = *(const float4*)&kT[(long long)row*512 + lane*8 + 4];
  float s = a.x+a.y+a.z+a.w + b.x+b.y+b.z+b.w;
  #pragma unroll
  for (int off = 1; off < 64; off <<= 1) s += __shfl_xor(s, off, 64);
  if (lane == 0) ksum[row] = s;
}

__global__ void k_dinv(const float* __restrict__ qp, const float* __restrict__ ksum,
                       float* __restrict__ dinv)
{
  const int tid = threadIdx.x;
  const int row = blockIdx.x*4 + (tid >> 6);
  const int lane = tid & 63;
  const int bh = row >> 9;
  float4 q = *(const float4*)&qp[(long long)row*256 + lane*4];
  float4 k = *(const float4*)&ksum[bh*256 + lane*4];
  float s = q.x*k.x + q.y*k.y + q.z*k.z + q.w*k.w;
  #pragma unroll
  for (int off = 1; off < 64; off <<= 1) s += __shfl_xor(s, off, 64);
  if (lane == 0) dinv[row] = 1.f / s;
}

// ---------------- pooling + classifier ----------------
__global__ void k_pool(const float* __restrict__ h, float* __restrict__ pooled)
{
  const int idx = blockIdx.x * 256 + threadIdx.x; // 8192
  const int b = idx >> 10, d = idx & 1023;
  const float* p = h + (long long)b * 524288 + d;
  float s0=0,s1=0,s2=0,s3=0;
  for (int t0 = 0; t0 < 512; t0 += 4) {
    s0 += p[(long long)(t0+0)*1024];
    s1 += p[(long long)(t0+1)*1024];
    s2 += p[(long long)(t0+2)*1024];
    s3 += p[(long long)(t0+3)*1024];
  }
  pooled[idx] = (s0+s1+s2+s3) * (1.f/512.f);
}

__global__ __launch_bounds__(256)
void k_cls(const float* __restrict__ pooled, const float* __restrict__ W1,
           const float* __restrict__ b1, const float* __restrict__ W2,
           const float* __restrict__ b2, float* __restrict__ out)
{
  const int b = blockIdx.x, tid = threadIdx.x;
  __shared__ float pl[1024];
  __shared__ float hd[512];
  *(float4*)&pl[tid*4] = *(const float4*)&pooled[b*1024 + tid*4];
  __syncthreads();
  for (int u = tid; u < 512; u += 256) {
    float acc = b1[u];
    for (int k = 0; k < 1024; ++k) acc = fmaf(pl[k], W1[(long long)k*512 + u], acc);
    hd[u] = fmaxf(acc, 0.f);
  }
  __syncthreads();
  if (tid < 2) {
    float acc = b2[tid];
    for (int k = 0; k < 512; ++k) acc = fmaf(hd[k], W2[k*2 + tid], acc);
    out[b*2 + tid] = acc;
  }
}

// ---------------- host ----------------
static float* symp(const void* s) { void* p = nullptr; (void)hipGetSymbolAddress(&p, s); return (float*)p; }

extern "C" void kernel_launch(void* const* d_in, const int* in_sizes, int n_in,
                              void* d_out, int out_size, void* d_ws, size_t ws_size,
                              hipStream_t stream)
{
  (void)in_sizes; (void)n_in; (void)d_ws; (void)ws_size; (void)out_size;
  const float* x     = (const float*)d_in[0];
  const float* l0Wih = (const float*)d_in[1];
  const float* l0Whh = (const float*)d_in[2];
  const float* l0bih = (const float*)d_in[3];
  const float* l0bhh = (const float*)d_in[4];
  const float* l1Wih = (const float*)d_in[5];
  const float* l1Whh = (const float*)d_in[6];
  const float* l1bih = (const float*)d_in[7];
  const float* l1bhh = (const float*)d_in[8];
  const float* proj  = (const float*)d_in[9];
  const float* ln1g  = (const float*)d_in[10];
  const float* ln1b  = (const float*)d_in[11];
  const float* Wq    = (const float*)d_in[12];
  const float* Wk    = (const float*)d_in[13];
  const float* Wv    = (const float*)d_in[14];
  const float* Wo    = (const float*)d_in[15];
  const float* bq    = (const float*)d_in[16];
  const float* bk    = (const float*)d_in[17];
  const float* bv    = (const float*)d_in[18];
  const float* bo    = (const float*)d_in[19];
  const float* ln2g  = (const float*)d_in[20];
  const float* ln2b  = (const float*)d_in[21];
  const float* Wf1   = (const float*)d_in[22];
  const float* bf1   = (const float*)d_in[23];
  const float* Wf2   = (const float*)d_in[24];
  const float* bf2   = (const float*)d_in[25];
  const float* cW1   = (const float*)d_in[26];
  const float* cb1   = (const float*)d_in[27];
  const float* cW2   = (const float*)d_in[28];
  const float* cb2   = (const float*)d_in[29];

  float* z0    = symp(HIP_SYMBOL(g_z0));
  float* z1    = symp(HIP_SYMBOL(g_z1));
  float* x1    = symp(HIP_SYMBOL(g_x1));
  float* hres  = symp(HIP_SYMBOL(g_hres));
  float* y     = symp(HIP_SYMBOL(g_y));
  float* qlin  = symp(HIP_SYMBOL(g_qlin));
  float* klin  = symp(HIP_SYMBOL(g_klin));
  float* vlin  = symp(HIP_SYMBOL(g_vlin));
  float* qp    = symp(HIP_SYMBOL(g_qp));
  float* ddb   = symp(HIP_SYMBOL(g_ddb));
  float* kT    = symp(HIP_SYMBOL(g_kT));
  float* ctx   = symp(HIP_SYMBOL(g_ctx));
  float* obuf  = symp(HIP_SYMBOL(g_obuf));
  float* ffb   = symp(HIP_SYMBOL(g_ffb));
  float* bs0   = symp(HIP_SYMBOL(g_bs0));
  float* bs1   = symp(HIP_SYMBOL(g_bs1));
  float* projs = symp(HIP_SYMBOL(g_projs));
  float* diagq = symp(HIP_SYMBOL(g_diagq));
  float* diagk = symp(HIP_SYMBOL(g_diagk));
  float* kmx   = symp(HIP_SYMBOL(g_kmx));
  float* ksum  = symp(HIP_SYMBOL(g_ksum));
  float* dinv  = symp(HIP_SYMBOL(g_dinv));
  float* hcur  = symp(HIP_SYMBOL(g_hcur));
  float* pooled= symp(HIP_SYMBOL(g_pooled));
  int*   bars  = (int*)symp(HIP_SYMBOL(g_bars));

  const float dn = 0.29730177875068026f; // 128^-0.25

  k_zero<<<1, 64, 0, stream>>>(bars);
  k_add2<<<16, 256, 0, stream>>>(bs0, l0bih, l0bhh, 4096);
  k_add2<<<16, 256, 0, stream>>>(bs1, l1bih, l1bhh, 4096);
  k_scale<<<128, 256, 0, stream>>>(projs, proj, dn, 32768);

  // LSTM layer 0: input projection + recurrence
  k_gemm<1,1><<<dim3(16,32,2), 256, 0, stream>>>(x, l0Wih, bs0, z0,
      4096, 2048, 256, 0LL, 2048LL*256, 8388608LL, 2048LL, nullptr);
  k_lstm<<<256, 256, 0, stream>>>(z0, l0Whh, x1, hcur, bars);

  // LSTM layer 1
  k_gemm<1,1><<<dim3(16,32,2), 256, 0, stream>>>(x1, l1Wih, bs1, z1,
      4096, 2048, 1024, 0LL, 2048LL*1024, 8388608LL, 2048LL, nullptr);
  k_lstm<<<256, 256, 0, stream>>>(z1, l1Whh, hres, hcur, bars + 32);

  for (int i = 0; i < 2; ++i) {
    const long long wOff = (long long)i * 1048576;
    // pre-norm attention
    k_ln<<<4096, 256, 0, stream>>>(hres, ln1g + i*1024, ln1b + i*1024, y);
    k_gemm<0,2><<<dim3(8,32,1), 256, 0, stream>>>(y, Wq + wOff, bq + i*1024, qlin,
        4096, 1024, 1024, 0LL, 0LL, 0LL, 0LL, nullptr);
    k_gemm<0,2><<<dim3(8,32,1), 256, 0, stream>>>(y, Wk + wOff, bk + i*1024, klin,
        4096, 1024, 1024, 0LL, 0LL, 0LL, 0LL, nullptr);
    k_gemm<0,2><<<dim3(8,32,1), 256, 0, stream>>>(y, Wv + wOff, bv + i*1024, vlin,
        4096, 1024, 1024, 0LL, 0LL, 0LL, 0LL, nullptr);
    k_diag<<<8192, 256, 0, stream>>>(qlin, diagq);
    k_diag<<<8192, 256, 0, stream>>>(klin, diagk);
    // FAVOR q
    k_gemm<1,0><<<dim3(2,256,1), 256, 0, stream>>>(qlin, projs, nullptr, qp,
        32768, 256, 128, 0LL, 0LL, 0LL, 0LL, nullptr);
    k_favq<<<8192, 256, 0, stream>>>(qp, diagq);
    // FAVOR k (block max, transpose)
    k_gemm<1,0><<<dim3(2,256,1), 256, 0, stream>>>(klin, projs, nullptr, ddb,
        32768, 256, 128, 0LL, 0LL, 0LL, 0LL, nullptr);
    k_kmax<<<64, 256, 0, stream>>>(ddb, kmx);
    k_fkT<<<dim3(16,8,64), dim3(32,8), 0, stream>>>(ddb, diagk, kmx, kT);
    k_ksum<<<4096, 256, 0, stream>>>(kT, ksum);
    // ctx = k'^T @ v  (batched over 64 heads)
    k_gemm<0,0><<<dim3(1,2,64), 256, 0, stream>>>(kT, vlin, nullptr, ctx,
        256, 128, 512, 131072LL, 65536LL, 32768LL, 0LL, nullptr);
    k_dinv<<<8192, 256, 0, stream>>>(qp, ksum, dinv);
    // o = (q' @ ctx) * dinv, merged heads
    k_gemm<0,5><<<dim3(1,4,64), 256, 0, stream>>>(qp, ctx, nullptr, obuf,
        512, 128, 256, 131072LL, 32768LL, 0LL, 0LL, dinv);
    // output projection + residual
    k_gemm<0,3><<<dim3(8,32,1), 256, 0, stream>>>(obuf, Wo + wOff, bo + i*1024, hres,
        4096, 1024, 1024, 0LL, 0LL, 0LL, 0LL, nullptr);
    // pre-norm FF
    k_ln<<<4096, 256, 0, stream>>>(hres, ln2g + i*1024, ln2b + i*1024, y);
    k_gemm<0,4><<<dim3(32,32,1), 256, 0, stream>>>(y, Wf1 + (long long)i*4194304, bf1 + i*4096, ffb,
        4096, 4096, 1024, 0LL, 0LL, 0LL, 0LL, nullptr);
    k_gemm<0,3><<<dim3(8,32,1), 256, 0, stream>>>(ffb, Wf2 + (long long)i*4194304, bf2 + i*1024, hres,
        4096, 1024, 4096, 0LL, 0LL, 0LL, 0LL, nullptr);
  }

  k_pool<<<32, 256, 0, stream>>>(hres, pooled);
  k_cls<<<8, 256, 0, stream>>>(pooled, cW1, cb1, cW2, cb2, (float*)d_out);
}

// Round 2
// 9532.708 us; speedup vs baseline: 2.9330x; 2.9330x over previous
//
#include <hip/hip_runtime.h>

#define KEPS 1e-4f

typedef __attribute__((ext_vector_type(8))) short bf16x8;
typedef __attribute__((ext_vector_type(4))) float f32x4;

// ---------------- static device workspace (allocated at module load) ----------------
__device__ float g_z0[2u*512*2048*8];     // layer0 input-proj Z [dir][t][4H][b]
__device__ float g_z1[2u*512*2048*8];
__device__ float g_x1[8u*512*1024];       // BiLSTM layer0 output [B,T,2H]
__device__ float g_hres[8u*512*1024];     // residual stream [B,T,D]
__device__ float g_y[8u*512*1024];        // LN output / scratch
__device__ float g_qlin[8u*8*512*128];    // [B,H,T,DH]
__device__ float g_klin[8u*8*512*128];
__device__ float g_vlin[8u*8*512*128];
__device__ float g_qp[8u*8*512*256];      // q' [B,H,T,M]
__device__ float g_ddb[8u*8*512*256];     // dd scratch for k
__device__ float g_kT[8u*8*256*512];      // k'^T [B,H,M,T]
__device__ float g_ctx[64u*256*128];      // [BH,M,DH]
__device__ float g_obuf[8u*512*1024];     // merged attention out [B,T,D]
__device__ float g_ffb[8u*512*4096];      // FF hidden [B*T,FF]
__device__ float g_bs0[2*2048];
__device__ float g_bs1[2*2048];
__device__ float g_projs[256*128];        // proj * dn
__device__ float g_diagq[32768];
__device__ float g_diagk[32768];
__device__ float g_kmx[64];
__device__ float g_ksum[64*256];
__device__ float g_dinv[32768];
__device__ unsigned g_hbuf[2*2*8*256];    // h exchange [buf][dir][b][256 u32 = 512 bf16]
__device__ float g_pooled[8*1024];
__device__ int   g_bars[64];              // software barrier counters

// ---------------- helpers ----------------
__device__ __forceinline__ float gelu_f(float x) {
  return 0.5f * x * (1.f + erff(x * 0.70710678118654752f));
}
__device__ __forceinline__ unsigned f2bf(float f) {
  unsigned x = __float_as_uint(f);
  return (x + 0x7FFFu + ((x >> 16) & 1u)) >> 16;   // RNE
}

__global__ void k_zero(int* p) { p[threadIdx.x] = 0; }

__global__ void k_add2(float* __restrict__ dst, const float* __restrict__ a,
                       const float* __restrict__ b, int n) {
  int i = blockIdx.x * 256 + threadIdx.x;
  if (i < n) dst[i] = a[i] + b[i];
}
__global__ void k_scale(float* __restrict__ dst, const float* __restrict__ a,
                        float s, int n) {
  int i = blockIdx.x * 256 + threadIdx.x;
  if (i < n) dst[i] = a[i] * s;
}

// ---------------- generic tiled fp32 GEMM ----------------
// C[M,N] = A[M,K] @ (BT ? W[N,K]^T : B[K,N]) + bias[N]
// MODE: 0 plain, 1 LSTM-Z store [dir][t][4H][b], 2 heads store [B,H,T,DH],
//       3 add-into-C (residual), 4 GELU, 5 o-store (dinv scale + head merge)
template<int BT, int MODE>
__global__ __launch_bounds__(256)
void k_gemm(const float* __restrict__ A, const float* __restrict__ Bw,
            const float* __restrict__ bias, float* __restrict__ C,
            int Mdim, int Ndim, int Kdim,
            long long aBS, long long bBS, long long cBS, long long biasBS,
            const float* __restrict__ aux)
{
  __shared__ float As[16][128];
  __shared__ float Bs[16][128];
  const int tid = threadIdx.x;
  const int tx = tid & 15, ty = tid >> 4;
  const int m0 = blockIdx.y * 128, n0 = blockIdx.x * 128;
  const int z = blockIdx.z;
  const float* Ab = A + (long long)z * aBS;
  const float* Bb = Bw + (long long)z * bBS;
  float acc[8][8] = {};

  for (int k0 = 0; k0 < Kdim; k0 += 16) {
    #pragma unroll
    for (int l0 = 0; l0 < 512; l0 += 256) {
      const int l = l0 + tid;
      const int r = l >> 2, kq = (l & 3) * 4;
      float4 v = *(const float4*)&Ab[(long long)(m0 + r) * Kdim + k0 + kq];
      As[kq+0][r] = v.x; As[kq+1][r] = v.y; As[kq+2][r] = v.z; As[kq+3][r] = v.w;
    }
    if (BT) {
      #pragma unroll
      for (int l0 = 0; l0 < 512; l0 += 256) {
        const int l = l0 + tid;
        const int r = l >> 2, kq = (l & 3) * 4;
        float4 v = *(const float4*)&Bb[(long long)(n0 + r) * Kdim + k0 + kq];
        Bs[kq+0][r] = v.x; Bs[kq+1][r] = v.y; Bs[kq+2][r] = v.z; Bs[kq+3][r] = v.w;
      }
    } else {
      #pragma unroll
      for (int l0 = 0; l0 < 512; l0 += 256) {
        const int l = l0 + tid;
        const int kr = l >> 5, n4 = (l & 31) * 4;
        *(float4*)&Bs[kr][n4] = *(const float4*)&Bb[(long long)(k0 + kr) * Ndim + n0 + n4];
      }
    }
    __syncthreads();
    #pragma unroll
    for (int kk = 0; kk < 16; ++kk) {
      float4 af0 = *(const float4*)&As[kk][ty*4];
      float4 af1 = *(const float4*)&As[kk][64 + ty*4];
      float4 bf0 = *(const float4*)&Bs[kk][tx*4];
      float4 bf1 = *(const float4*)&Bs[kk][64 + tx*4];
      float av[8] = {af0.x,af0.y,af0.z,af0.w,af1.x,af1.y,af1.z,af1.w};
      float bv[8] = {bf0.x,bf0.y,bf0.z,bf0.w,bf1.x,bf1.y,bf1.z,bf1.w};
      #pragma unroll
      for (int i = 0; i < 8; ++i)
        #pragma unroll
        for (int j = 0; j < 8; ++j)
          acc[i][j] = fmaf(av[i], bv[j], acc[i][j]);
    }
    __syncthreads();
  }

  float bias0[4] = {0.f,0.f,0.f,0.f}, bias1[4] = {0.f,0.f,0.f,0.f};
  if (MODE != 5 && bias != nullptr) {
    const float* bz = bias + (long long)z * biasBS;
    float4 t0 = *(const float4*)&bz[n0 + tx*4];
    float4 t1 = *(const float4*)&bz[n0 + 64 + tx*4];
    bias0[0]=t0.x; bias0[1]=t0.y; bias0[2]=t0.z; bias0[3]=t0.w;
    bias1[0]=t1.x; bias1[1]=t1.y; bias1[2]=t1.z; bias1[3]=t1.w;
  }
  float* Cz = C + (long long)z * cBS;
  #pragma unroll
  for (int i = 0; i < 8; ++i) {
    const int m = m0 + ((i < 4) ? (ty*4 + i) : (64 + ty*4 + (i - 4)));
    #pragma unroll
    for (int jb = 0; jb < 2; ++jb) {
      const int ci = n0 + (jb ? 64 : 0) + tx*4;
      float4 v;
      v.x = acc[i][jb*4+0] + (jb ? bias1[0] : bias0[0]);
      v.y = acc[i][jb*4+1] + (jb ? bias1[1] : bias0[1]);
      v.z = acc[i][jb*4+2] + (jb ? bias1[2] : bias0[2]);
      v.w = acc[i][jb*4+3] + (jb ? bias1[3] : bias0[3]);
      if (MODE == 4) { v.x = gelu_f(v.x); v.y = gelu_f(v.y); v.z = gelu_f(v.z); v.w = gelu_f(v.w); }
      if (MODE == 0 || MODE == 4) {
        *(float4*)&Cz[(long long)m * Ndim + ci] = v;
      } else if (MODE == 3) {
        float4 o4 = *(const float4*)&Cz[(long long)m * Ndim + ci];
        v.x += o4.x; v.y += o4.y; v.z += o4.z; v.w += o4.w;
        *(float4*)&Cz[(long long)m * Ndim + ci] = v;
      } else if (MODE == 1) {
        const int b_ = m >> 9, t_ = m & 511;
        float vv[4] = {v.x, v.y, v.z, v.w};
        #pragma unroll
        for (int c = 0; c < 4; ++c)
          Cz[((long long)t_*2048 + ci + c)*8 + b_] = vv[c];
      } else if (MODE == 2) {
        const int b_ = m >> 9, t_ = m & 511;
        const int hd = ci >> 7;
        *(float4*)&Cz[(((long long)(b_*8 + hd))*512 + t_)*128 + (ci & 127)] = v;
      } else if (MODE == 5) {
        const int b_ = z >> 3, hd = z & 7;
        const float sc = aux[(long long)z*512 + m];
        v.x *= sc; v.y *= sc; v.z *= sc; v.w *= sc;
        *(float4*)&Cz[((long long)(b_*512 + m))*1024 + hd*128 + ci] = v;
      }
    }
  }
}

// ---------------- persistent BiLSTM recurrence v2 (MFMA, 16 WGs/direction) -------
// grid = 32 WGs: blockIdx = dir*16 + slice. Each WG owns 32 hidden units.
// Whh slice (128 gate rows x 512) resident in LDS as bf16 (swizzled 8-blocks).
// Per step: gates[128x8] = W_lds @ h (mfma 16x16x32 bf16), combine, 8KB bf16
// h-exchange through L2/L3 with a 16-WG atomic barrier per direction.
__global__ __launch_bounds__(512)
void k_lstm2(const float* __restrict__ Z, const float* __restrict__ Whh,
             float* __restrict__ outh, unsigned* __restrict__ hbufU,
             int* __restrict__ barBase)
{
  extern __shared__ char smem[];
  short*          Wl    = (short*)smem;                       // 128*512 bf16 = 131072 B
  short*          hl    = (short*)(smem + 131072);            // 8*512 bf16  = 8192 B
  float*          gates = (float*)(smem + 139264);            // 128*8 f32   = 4096 B
  unsigned short* houts = (unsigned short*)(smem + 143360);   // 8*32        = 512 B

  const int slice = blockIdx.x & 15, dir = blockIdx.x >> 4;
  const int tid = threadIdx.x;
  const int u0 = slice * 32;
  int* bar = barBase + dir * 16;

  // stage Whh slice -> LDS bf16, row lr = gate*32 + j, 8-elem blocks rotated by lr
  for (int blk = tid; blk < 8192; blk += 512) {
    const int lr = blk >> 6, bi = blk & 63;
    const long long src = ((long long)dir*2048 + (lr>>5)*512 + u0 + (lr&31))*512 + bi*8;
    float4 w0 = *(const float4*)&Whh[src];
    float4 w1 = *(const float4*)&Whh[src + 4];
    unsigned* dst = (unsigned*)&Wl[lr*512 + (((bi + lr) & 63) << 3)];
    dst[0] = f2bf(w0.x) | (f2bf(w0.y) << 16);
    dst[1] = f2bf(w0.z) | (f2bf(w0.w) << 16);
    dst[2] = f2bf(w1.x) | (f2bf(w1.y) << 16);
    dst[3] = f2bf(w1.z) | (f2bf(w1.w) << 16);
  }
  // zero h_lds (t=0 state)
  for (int i = tid; i < 2048; i += 512) ((unsigned*)hl)[i] = 0u;

  const int wv = tid >> 6, l = tid & 63;
  const int arow = wv*16 + (l & 15);
  const int bb   = l & 7;
  const int qoff = l >> 4;
  const int jj = tid >> 3, bcomb = tid & 7;   // combine mapping (tid<256)
  float cst = 0.f;

  for (int s = 0; s < 512; ++s) {
    const int t = dir ? (511 - s) : s;
    // early-issue Z loads (fp32, layout [dir][t][row][b])
    float z0v = 0.f, z1v = 0.f, z2v = 0.f, z3v = 0.f;
    if (tid < 256) {
      const float* zp = Z + (((long long)dir*512 + t)*16384) + (u0 + jj)*8 + bcomb;
      z0v = zp[0]; z1v = zp[4096]; z2v = zp[8192]; z3v = zp[12288];
    }
    // gather h (bf16) from exchange buffer into swizzled LDS
    if (s > 0) {
      const unsigned base = ((unsigned)((s & 1)*2 + dir)) * 2048;
      #pragma unroll
      for (int q = 0; q < 4; ++q) {
        const int gidx = q*512 + tid;          // 0..2047
        const int b = gidx >> 8, p = gidx & 255;
        unsigned v = __hip_atomic_load(&hbufU[base + b*256 + p],
                                       __ATOMIC_RELAXED, __HIP_MEMORY_SCOPE_AGENT);
        const int bi = p >> 2;
        *(unsigned*)&hl[b*512 + (((bi + b) & 63) << 3) + ((p & 3) << 1)] = v;
      }
    }
    __syncthreads();
    // gates = W @ h via mfma 16x16x32 bf16 (D: row=gate-row, col=batch)
    f32x4 acc = {0.f, 0.f, 0.f, 0.f};
    #pragma unroll
    for (int ks = 0; ks < 16; ++ks) {
      const int qb = ks*4 + qoff;
      bf16x8 av = *(bf16x8*)&Wl[arow*512 + (((qb + arow) & 63) << 3)];
      bf16x8 bv = *(bf16x8*)&hl[bb*512   + (((qb + bb)   & 63) << 3)];
      acc = __builtin_amdgcn_mfma_f32_16x16x32_bf16(av, bv, acc, 0, 0, 0);
    }
    const int bcol = l & 15;
    if (bcol < 8) {
      #pragma unroll
      for (int r = 0; r < 4; ++r)
        gates[(wv*16 + qoff*4 + r)*8 + bcol] = acc[r];
    }
    __syncthreads();
    // combine: thread (j,b) owns unit u0+j, batch b; cell state in register
    if (tid < 256) {
      const float gi = gates[jj*8        + bcomb] + z0v;
      const float gf = gates[(32+jj)*8   + bcomb] + z1v;
      const float gg = gates[(64+jj)*8   + bcomb] + z2v;
      const float go = gates[(96+jj)*8   + bcomb] + z3v;
      const float ig = 1.f/(1.f + expf(-gi));
      const float fg = 1.f/(1.f + expf(-gf));
      const float og = 1.f/(1.f + expf(-go));
      cst = fg*cst + ig*tanhf(gg);
      const float hv = og*tanhf(cst);
      outh[((long long)(bcomb*512 + t))*1024 + (dir<<9) + u0 + jj] = hv;
      houts[bcomb*32 + jj] = (unsigned short)f2bf(hv);
    }
    __syncthreads();
    // publish h slice (128 u32 = 32 units x 8 batches)
    if (tid < 128) {
      const int b = tid >> 4, i = tid & 15;
      const unsigned v = (unsigned)houts[b*32 + 2*i] | ((unsigned)houts[b*32 + 2*i + 1] << 16);
      const unsigned base = ((unsigned)(((s+1) & 1)*2 + dir)) * 2048;
      __hip_atomic_store(&hbufU[base + b*256 + (u0 >> 1) + i], v,
                         __ATOMIC_RELAXED, __HIP_MEMORY_SCOPE_AGENT);
    }
    // 16-WG barrier for this direction
    if (s != 511) {
      __syncthreads();
      if (tid == 0) {
        __threadfence();
        __hip_atomic_fetch_add(bar, 1, __ATOMIC_RELEASE, __HIP_MEMORY_SCOPE_AGENT);
        const int need = 16*(s + 1);
        while (__hip_atomic_load(bar, __ATOMIC_ACQUIRE, __HIP_MEMORY_SCOPE_AGENT) < need)
          __builtin_amdgcn_s_sleep(1);
      }
      __syncthreads();
    }
  }
}

// ---------------- LayerNorm (one row of 1024 per block) ----------------
__global__ __launch_bounds__(256)
void k_ln(const float* __restrict__ X, const float* __restrict__ gw,
          const float* __restrict__ bw, float* __restrict__ Y)
{
  const int row = blockIdx.x, tid = threadIdx.x;
  const float* xr = X + (long long)row * 1024;
  float4 v = *(const float4*)&xr[tid*4];
  float s  = v.x + v.y + v.z + v.w;
  float ss = v.x*v.x + v.y*v.y + v.z*v.z + v.w*v.w;
  #pragma unroll
  for (int off = 1; off < 64; off <<= 1) {
    s  += __shfl_xor(s, off, 64);
    ss += __shfl_xor(ss, off, 64);
  }
  __shared__ float rs[4], rss[4];
  const int w = tid >> 6;
  if ((tid & 63) == 0) { rs[w] = s; rss[w] = ss; }
  __syncthreads();
  s  = rs[0] + rs[1] + rs[2] + rs[3];
  ss = rss[0] + rss[1] + rss[2] + rss[3];
  const float mu = s * (1.f/1024.f);
  const float var = ss * (1.f/1024.f) - mu*mu;
  const float rstd = rsqrtf(var + 1e-5f);
  float4 g4 = *(const float4*)&gw[tid*4];
  float4 b4 = *(const float4*)&bw[tid*4];
  float4 o;
  o.x = (v.x - mu)*rstd*g4.x + b4.x;
  o.y = (v.y - mu)*rstd*g4.y + b4.y;
  o.z = (v.z - mu)*rstd*g4.z + b4.z;
  o.w = (v.w - mu)*rstd*g4.w + b4.w;
  *(float4*)&Y[(long long)row*1024 + tid*4] = o;
}

// ---------------- FAVOR helpers ----------------
__global__ void k_diag(const float* __restrict__ X, float* __restrict__ dout)
{
  const int tid = threadIdx.x;
  const int row = blockIdx.x*4 + (tid >> 6);
  const int lane = tid & 63;
  float2 v = *(const float2*)&X[(long long)row*128 + lane*2];
  float ss = v.x*v.x + v.y*v.y;
  #pragma unroll
  for (int off = 1; off < 64; off <<= 1) ss += __shfl_xor(ss, off, 64);
  if (lane == 0) dout[row] = ss * 0.044194173824159216f; // 0.5 * dn^2, dn=128^-0.25
}

__global__ void k_favq(float* __restrict__ dd, const float* __restrict__ diag)
{
  const int tid = threadIdx.x;
  const int row = blockIdx.x*4 + (tid >> 6);
  const int lane = tid & 63;
  float4 v = *(const float4*)&dd[(long long)row*256 + lane*4];
  float mx = fmaxf(fmaxf(v.x, v.y), fmaxf(v.z, v.w));
  #pragma unroll
  for (int off = 1; off < 64; off <<= 1) mx = fmaxf(mx, __shfl_xor(mx, off, 64));
  const float dg = diag[row];
  float4 o;
  o.x = (expf(v.x - dg - mx) + KEPS)*0.0625f;
  o.y = (expf(v.y - dg - mx) + KEPS)*0.0625f;
  o.z = (expf(v.z - dg - mx) + KEPS)*0.0625f;
  o.w = (expf(v.w - dg - mx) + KEPS)*0.0625f;
  *(float4*)&dd[(long long)row*256 + lane*4] = o;
}

__global__ __launch_bounds__(256)
void k_kmax(const float* __restrict__ dd, float* __restrict__ kmx)
{
  const int bh = blockIdx.x, tid = threadIdx.x;
  const float* p = dd + (long long)bh * 131072;
  float mx = -3.4e38f;
  for (int i = tid*4; i < 131072; i += 1024) {
    float4 v = *(const float4*)&p[i];
    mx = fmaxf(mx, fmaxf(fmaxf(v.x, v.y), fmaxf(v.z, v.w)));
  }
  #pragma unroll
  for (int off = 1; off < 64; off <<= 1) mx = fmaxf(mx, __shfl_xor(mx, off, 64));
  __shared__ float red[4];
  if ((tid & 63) == 0) red[tid >> 6] = mx;
  __syncthreads();
  if (tid == 0) kmx[bh] = fmaxf(fmaxf(red[0], red[1]), fmaxf(red[2], red[3]));
}

__global__ void k_fkT(const float* __restrict__ dd, const float* __restrict__ diag,
                      const float* __restrict__ kmx, float* __restrict__ kT)
{
  __shared__ float tile[32][33];
  const int bh = blockIdx.z;
  const int t0 = blockIdx.x * 32, m0 = blockIdx.y * 32;
  const int tx = threadIdx.x, ty = threadIdx.y;
  const float km = kmx[bh];
  #pragma unroll
  for (int j = 0; j < 4; ++j) {
    const int t = t0 + ty + j*8;
    const float v = dd[((long long)bh*512 + t)*256 + m0 + tx];
    tile[ty + j*8][tx] = (expf(v - diag[bh*512 + t] - km) + KEPS) * 0.0625f;
  }
  __syncthreads();
  #pragma unroll
  for (int j = 0; j < 4; ++j) {
    const int m = m0 + ty + j*8;
    kT[((long long)bh*256 + m)*512 + t0 + tx] = tile[tx][ty + j*8];
  }
}

__global__ void k_ksum(const float* __restrict__ kT, float* __restrict__ ksum)
{
  const int tid = threadIdx.x;
  const int row = blockIdx.x*4 + (tid >> 6);
  const int lane = tid & 63;
  float4 a = *(const float4*)&kT[(long long)row*512 + lane*8];
  float4 b = *(const float4*)&kT[(long long)row*512 + lane*8 + 4];
  float s = a.x+a.y+a.z+a.w + b.x+b.y+b.z+b.w;
  #pragma unroll
  for (int off = 1; off < 64; off <<= 1) s += __shfl_xor(s, off, 64);
  if (lane == 0) ksum[row] = s;
}

__global__ void k_dinv(const float* __restrict__ qp, const float* __restrict__ ksum,
                       float* __restrict__ dinv)
{
  const int tid = threadIdx.x;
  const int row = blockIdx.x*4 + (tid >> 6);
  const int lane = tid & 63;
  const int bh = row >> 9;
  float4 q = *(const float4*)&qp[(long long)row*256 + lane*4];
  float4 k = *(const float4*)&ksum[bh*256 + lane*4];
  float s = q.x*k.x + q.y*k.y + q.z*k.z + q.w*k.w;
  #pragma unroll
  for (int off = 1; off < 64; off <<= 1) s += __shfl_xor(s, off, 64);
  if (lane == 0) dinv[row] = 1.f / s;
}

// ---------------- pooling + classifier ----------------
__global__ void k_pool(const float* __restrict__ h, float* __restrict__ pooled)
{
  const int idx = blockIdx.x * 256 + threadIdx.x; // 8192
  const int b = idx >> 10, d = idx & 1023;
  const float* p = h + (long long)b * 524288 + d;
  float s0=0,s1=0,s2=0,s3=0;
  for (int t0 = 0; t0 < 512; t0 += 4) {
    s0 += p[(long long)(t0+0)*1024];
    s1 += p[(long long)(t0+1)*1024];
    s2 += p[(long long)(t0+2)*1024];
    s3 += p[(long long)(t0+3)*1024];
  }
  pooled[idx] = (s0+s1+s2+s3) * (1.f/512.f);
}

__global__ __launch_bounds__(256)
void k_cls(const float* __restrict__ pooled, const float* __restrict__ W1,
           const float* __restrict__ b1, const float* __restrict__ W2,
           const float* __restrict__ b2, float* __restrict__ out)
{
  const int b = blockIdx.x, tid = threadIdx.x;
  __shared__ float pl[1024];
  __shared__ float hd[512];
  *(float4*)&pl[tid*4] = *(const float4*)&pooled[b*1024 + tid*4];
  __syncthreads();
  for (int u = tid; u < 512; u += 256) {
    float acc = b1[u];
    for (int k = 0; k < 1024; ++k) acc = fmaf(pl[k], W1[(long long)k*512 + u], acc);
    hd[u] = fmaxf(acc, 0.f);
  }
  __syncthreads();
  if (tid < 2) {
    float acc = b2[tid];
    for (int k = 0; k < 512; ++k) acc = fmaf(hd[k], W2[k*2 + tid], acc);
    out[b*2 + tid] = acc;
  }
}

// ---------------- host ----------------
static float* symp(const void* s) { void* p = nullptr; (void)hipGetSymbolAddress(&p, s); return (float*)p; }

extern "C" void kernel_launch(void* const* d_in, const int* in_sizes, int n_in,
                              void* d_out, int out_size, void* d_ws, size_t ws_size,
                              hipStream_t stream)
{
  (void)in_sizes; (void)n_in; (void)d_ws; (void)ws_size; (void)out_size;
  const float* x     = (const float*)d_in[0];
  const float* l0Wih = (const float*)d_in[1];
  const float* l0Whh = (const float*)d_in[2];
  const float* l0bih = (const float*)d_in[3];
  const float* l0bhh = (const float*)d_in[4];
  const float* l1Wih = (const float*)d_in[5];
  const float* l1Whh = (const float*)d_in[6];
  const float* l1bih = (const float*)d_in[7];
  const float* l1bhh = (const float*)d_in[8];
  const float* proj  = (const float*)d_in[9];
  const float* ln1g  = (const float*)d_in[10];
  const float* ln1b  = (const float*)d_in[11];
  const float* Wq    = (const float*)d_in[12];
  const float* Wk    = (const float*)d_in[13];
  const float* Wv    = (const float*)d_in[14];
  const float* Wo    = (const float*)d_in[15];
  const float* bq    = (const float*)d_in[16];
  const float* bk    = (const float*)d_in[17];
  const float* bv    = (const float*)d_in[18];
  const float* bo    = (const float*)d_in[19];
  const float* ln2g  = (const float*)d_in[20];
  const float* ln2b  = (const float*)d_in[21];
  const float* Wf1   = (const float*)d_in[22];
  const float* bf1   = (const float*)d_in[23];
  const float* Wf2   = (const float*)d_in[24];
  const float* bf2   = (const float*)d_in[25];
  const float* cW1   = (const float*)d_in[26];
  const float* cb1   = (const float*)d_in[27];
  const float* cW2   = (const float*)d_in[28];
  const float* cb2   = (const float*)d_in[29];

  float* z0    = symp(HIP_SYMBOL(g_z0));
  float* z1    = symp(HIP_SYMBOL(g_z1));
  float* x1    = symp(HIP_SYMBOL(g_x1));
  float* hres  = symp(HIP_SYMBOL(g_hres));
  float* y     = symp(HIP_SYMBOL(g_y));
  float* qlin  = symp(HIP_SYMBOL(g_qlin));
  float* klin  = symp(HIP_SYMBOL(g_klin));
  float* vlin  = symp(HIP_SYMBOL(g_vlin));
  float* qp    = symp(HIP_SYMBOL(g_qp));
  float* ddb   = symp(HIP_SYMBOL(g_ddb));
  float* kT    = symp(HIP_SYMBOL(g_kT));
  float* ctx   = symp(HIP_SYMBOL(g_ctx));
  float* obuf  = symp(HIP_SYMBOL(g_obuf));
  float* ffb   = symp(HIP_SYMBOL(g_ffb));
  float* bs0   = symp(HIP_SYMBOL(g_bs0));
  float* bs1   = symp(HIP_SYMBOL(g_bs1));
  float* projs = symp(HIP_SYMBOL(g_projs));
  float* diagq = symp(HIP_SYMBOL(g_diagq));
  float* diagk = symp(HIP_SYMBOL(g_diagk));
  float* kmx   = symp(HIP_SYMBOL(g_kmx));
  float* ksum  = symp(HIP_SYMBOL(g_ksum));
  float* dinv  = symp(HIP_SYMBOL(g_dinv));
  unsigned* hbuf = (unsigned*)symp(HIP_SYMBOL(g_hbuf));
  float* pooled= symp(HIP_SYMBOL(g_pooled));
  int*   bars  = (int*)symp(HIP_SYMBOL(g_bars));

  const float dn = 0.29730177875068026f; // 128^-0.25
  const int LSTM_LDS = 143872;

  (void)hipFuncSetAttribute(reinterpret_cast<const void*>(k_lstm2),
                            hipFuncAttributeMaxDynamicSharedMemorySize, LSTM_LDS);

  k_zero<<<1, 64, 0, stream>>>(bars);
  k_add2<<<16, 256, 0, stream>>>(bs0, l0bih, l0bhh, 4096);
  k_add2<<<16, 256, 0, stream>>>(bs1, l1bih, l1bhh, 4096);
  k_scale<<<128, 256, 0, stream>>>(projs, proj, dn, 32768);

  // LSTM layer 0: input projection + recurrence
  k_gemm<1,1><<<dim3(16,32,2), 256, 0, stream>>>(x, l0Wih, bs0, z0,
      4096, 2048, 256, 0LL, 2048LL*256, 8388608LL, 2048LL, nullptr);
  k_lstm2<<<32, 512, LSTM_LDS, stream>>>(z0, l0Whh, x1, hbuf, bars);

  // LSTM layer 1
  k_gemm<1,1><<<dim3(16,32,2), 256, 0, stream>>>(x1, l1Wih, bs1, z1,
      4096, 2048, 1024, 0LL, 2048LL*1024, 8388608LL, 2048LL, nullptr);
  k_lstm2<<<32, 512, LSTM_LDS, stream>>>(z1, l1Whh, hres, hbuf, bars + 32);

  for (int i = 0; i < 2; ++i) {
    const long long wOff = (long long)i * 1048576;
    // pre-norm attention
    k_ln<<<4096, 256, 0, stream>>>(hres, ln1g + i*1024, ln1b + i*1024, y);
    k_gemm<0,2><<<dim3(8,32,1), 256, 0, stream>>>(y, Wq + wOff, bq + i*1024, qlin,
        4096, 1024, 1024, 0LL, 0LL, 0LL, 0LL, nullptr);
    k_gemm<0,2><<<dim3(8,32,1), 256, 0, stream>>>(y, Wk + wOff, bk + i*1024, klin,
        4096, 1024, 1024, 0LL, 0LL, 0LL, 0LL, nullptr);
    k_gemm<0,2><<<dim3(8,32,1), 256, 0, stream>>>(y, Wv + wOff, bv + i*1024, vlin,
        4096, 1024, 1024, 0LL, 0LL, 0LL, 0LL, nullptr);
    k_diag<<<8192, 256, 0, stream>>>(qlin, diagq);
    k_diag<<<8192, 256, 0, stream>>>(klin, diagk);
    // FAVOR q
    k_gemm<1,0><<<dim3(2,256,1), 256, 0, stream>>>(qlin, projs, nullptr, qp,
        32768, 256, 128, 0LL, 0LL, 0LL, 0LL, nullptr);
    k_favq<<<8192, 256, 0, stream>>>(qp, diagq);
    // FAVOR k (block max, transpose)
    k_gemm<1,0><<<dim3(2,256,1), 256, 0, stream>>>(klin, projs, nullptr, ddb,
        32768, 256, 128, 0LL, 0LL, 0LL, 0LL, nullptr);
    k_kmax<<<64, 256, 0, stream>>>(ddb, kmx);
    k_fkT<<<dim3(16,8,64), dim3(32,8), 0, stream>>>(ddb, diagk, kmx, kT);
    k_ksum<<<4096, 256, 0, stream>>>(kT, ksum);
    // ctx = k'^T @ v  (batched over 64 heads)
    k_gemm<0,0><<<dim3(1,2,64), 256, 0, stream>>>(kT, vlin, nullptr, ctx,
        256, 128, 512, 131072LL, 65536LL, 32768LL, 0LL, nullptr);
    k_dinv<<<8192, 256, 0, stream>>>(qp, ksum, dinv);
    // o = (q' @ ctx) * dinv, merged heads
    k_gemm<0,5><<<dim3(1,4,64), 256, 0, stream>>>(qp, ctx, nullptr, obuf,
        512, 128, 256, 131072LL, 32768LL, 0LL, 0LL, dinv);
    // output projection + residual
    k_gemm<0,3><<<dim3(8,32,1), 256, 0, stream>>>(obuf, Wo + wOff, bo + i*1024, hres,
        4096, 1024, 1024, 0LL, 0LL, 0LL, 0LL, nullptr);
    // pre-norm FF
    k_ln<<<4096, 256, 0, stream>>>(hres, ln2g + i*1024, ln2b + i*1024, y);
    k_gemm<0,4><<<dim3(32,32,1), 256, 0, stream>>>(y, Wf1 + (long long)i*4194304, bf1 + i*4096, ffb,
        4096, 4096, 1024, 0LL, 0LL, 0LL, 0LL, nullptr);
    k_gemm<0,3><<<dim3(8,32,1), 256, 0, stream>>>(ffb, Wf2 + (long long)i*4194304, bf2 + i*1024, hres,
        4096, 1024, 4096, 0LL, 0LL, 0LL, 0LL, nullptr);
  }

  k_pool<<<32, 256, 0, stream>>>(hres, pooled);
  k_cls<<<8, 256, 0, stream>>>(pooled, cW1, cb1, cW2, cb2, (float*)d_out);
}

// Round 3
// 6959.404 us; speedup vs baseline: 4.0175x; 1.3698x over previous
//
#include <hip/hip_runtime.h>

#define KEPS 1e-4f

typedef __attribute__((ext_vector_type(8))) short bf16x8;
typedef __attribute__((ext_vector_type(4))) float f32x4;
typedef unsigned short u16;

// ---------------- static device workspace ----------------
__device__ float g_z0[2u*512*2048*8];     // layer0 input-proj Z [dir][t][4H][b]
__device__ float g_z1[2u*512*2048*8];
__device__ float g_hres[8u*512*1024];     // residual stream [B,T,D] fp32
__device__ float g_y[8u*512*1024];        // LN output fp32 (Wq/Wk path)
__device__ float g_qlin[8u*8*512*128];    // [B,H,T,DH]
__device__ float g_klin[8u*8*512*128];
__device__ float g_vlin[8u*8*512*128];
__device__ float g_qp[8u*8*512*256];      // q' [B,H,T,M]
__device__ float g_ddb[8u*8*512*256];
__device__ float g_kT[8u*8*256*512];      // k'^T [B,H,M,T]
__device__ float g_ctx[64u*256*128];      // [BH,M,DH]
__device__ float g_bs0[2*2048];
__device__ float g_bs1[2*2048];
__device__ float g_projs[256*128];
__device__ float g_diagq[32768];
__device__ float g_diagk[32768];
__device__ float g_kmx[64];
__device__ float g_ksum[64*256];
__device__ float g_dinv[32768];
__device__ unsigned g_hbuf[2*2*8*256];    // h exchange [slot][dir][b][256 u32]
__device__ float g_pooled[8*1024];
__device__ unsigned g_flags[1024];        // [layer][dir][slice] flags, 64B padded

// bf16 buffers
__device__ u16 g_xbf[8u*512*256];
__device__ u16 g_x1bf[8u*512*1024];
__device__ u16 g_ybf[8u*512*1024];
__device__ u16 g_obufbf[8u*512*1024];
__device__ u16 g_ffbbf[8u*512*4096];
__device__ u16 g_wih0b[2u*2048*256];
__device__ u16 g_wih1b[2u*2048*1024];
__device__ u16 g_wvt[2u*1024*1024];       // [layer][N=out][K=in]
__device__ u16 g_wot[2u*1024*1024];
__device__ u16 g_wf1t[2u*4096*1024];
__device__ u16 g_wf2t[2u*1024*4096];

// ---------------- helpers ----------------
__device__ __forceinline__ float gelu_f(float x) {
  return 0.5f * x * (1.f + erff(x * 0.70710678118654752f));
}
__device__ __forceinline__ unsigned f2bf(float f) {
  unsigned x = __float_as_uint(f);
  return (x + 0x7FFFu + ((x >> 16) & 1u)) >> 16;   // RNE
}

__global__ void k_zero(int* p) { p[blockIdx.x*256 + threadIdx.x] = 0; }

__global__ void k_add2(float* __restrict__ dst, const float* __restrict__ a,
                       const float* __restrict__ b, int n) {
  int i = blockIdx.x * 256 + threadIdx.x;
  if (i < n) dst[i] = a[i] + b[i];
}
__global__ void k_scale(float* __restrict__ dst, const float* __restrict__ a,
                        float s, int n) {
  int i = blockIdx.x * 256 + threadIdx.x;
  if (i < n) dst[i] = a[i] * s;
}
__global__ void k_cvt(const float* __restrict__ src, u16* __restrict__ dst, int n4) {
  int i = blockIdx.x * 256 + threadIdx.x;
  if (i < n4) {
    float4 v = ((const float4*)src)[i];
    ushort4 o; o.x=(u16)f2bf(v.x); o.y=(u16)f2bf(v.y); o.z=(u16)f2bf(v.z); o.w=(u16)f2bf(v.w);
    ((ushort4*)dst)[i] = o;
  }
}
// fp32 [K][N] -> bf16 [N][K]
__global__ void k_w2bfT(const float* __restrict__ src, u16* __restrict__ dst,
                        int K, int N, long long sBS, long long dBS)
{
  __shared__ float tile[32][33];
  const int z = blockIdx.z;
  const int n0 = blockIdx.x*32, k0 = blockIdx.y*32;
  const int tx = threadIdx.x, ty = threadIdx.y;
  const float* s = src + (long long)z*sBS;
  u16* d = dst + (long long)z*dBS;
  #pragma unroll
  for (int j = 0; j < 4; ++j)
    tile[ty + j*8][tx] = s[(long long)(k0 + ty + j*8)*N + n0 + tx];
  __syncthreads();
  #pragma unroll
  for (int j = 0; j < 4; ++j)
    d[(long long)(n0 + ty + j*8)*K + k0 + tx] = (u16)f2bf(tile[tx][ty + j*8]);
}

// ---------------- bf16 MFMA GEMM ----------------
// C[M,N] = A[M,K](bf16) @ B[N,K](bf16)^T + bias
// MODE: 0 plain f32, 1 Z-scatter f32 [t][4H][b], 2 heads f32 [B,H,T,DH],
//       3 add-into f32 C, 4 GELU -> bf16
template<int MODE>
__global__ __launch_bounds__(256)
void k_bgemm(const u16* __restrict__ A, const u16* __restrict__ Bw,
             const float* __restrict__ bias, void* __restrict__ Cv,
             int Ndim, int Kdim,
             long long aBS, long long bBS, long long cBS, long long biasBS)
{
  __shared__ __align__(16) u16 As[128*40];
  __shared__ __align__(16) u16 Bs[128*40];
  const int tid = threadIdx.x;
  const int m0 = blockIdx.y * 128, n0 = blockIdx.x * 128, z = blockIdx.z;
  const u16* Ab = A + (long long)z*aBS;
  const u16* Bb = Bw + (long long)z*bBS;
  const int wv = tid >> 6, l = tid & 63;
  const int wm = wv >> 1, wn = wv & 1;
  const int lr = l & 15, lk = l >> 4;
  const int str = tid >> 2, stc = (tid & 3)*8;
  f32x4 acc[4][4];
  #pragma unroll
  for (int i=0;i<4;++i)
    #pragma unroll
    for (int j=0;j<4;++j) acc[i][j] = (f32x4){0.f,0.f,0.f,0.f};

  for (int k0 = 0; k0 < Kdim; k0 += 32) {
    #pragma unroll
    for (int q = 0; q < 2; ++q) {
      const int r = q*64 + str;
      *(uint4*)&As[r*40 + stc] = *(const uint4*)&Ab[(long long)(m0 + r)*Kdim + k0 + stc];
      *(uint4*)&Bs[r*40 + stc] = *(const uint4*)&Bb[(long long)(n0 + r)*Kdim + k0 + stc];
    }
    __syncthreads();
    bf16x8 af[4], bfr[4];
    #pragma unroll
    for (int i=0;i<4;++i) af[i]  = *(bf16x8*)&As[(wm*64 + i*16 + lr)*40 + lk*8];
    #pragma unroll
    for (int j=0;j<4;++j) bfr[j] = *(bf16x8*)&Bs[(wn*64 + j*16 + lr)*40 + lk*8];
    #pragma unroll
    for (int i=0;i<4;++i)
      #pragma unroll
      for (int j=0;j<4;++j)
        acc[i][j] = __builtin_amdgcn_mfma_f32_16x16x32_bf16(af[i], bfr[j], acc[i][j], 0, 0, 0);
    __syncthreads();
  }

  #pragma unroll
  for (int j=0;j<4;++j) {
    const int n = n0 + wn*64 + j*16 + lr;
    const float bvv = bias ? bias[(long long)z*biasBS + n] : 0.f;
    #pragma unroll
    for (int i=0;i<4;++i) {
      #pragma unroll
      for (int r=0;r<4;++r) {
        const int m = m0 + wm*64 + i*16 + lk*4 + r;
        float v = acc[i][j][r] + bvv;
        if (MODE == 0) {
          ((float*)Cv)[(long long)z*cBS + (long long)m*Ndim + n] = v;
        } else if (MODE == 1) {
          const int b_ = m >> 9, t_ = m & 511;
          ((float*)Cv)[(long long)z*cBS + ((long long)t_*2048 + n)*8 + b_] = v;
        } else if (MODE == 2) {
          const int b_ = m >> 9, t_ = m & 511;
          const int hd = n >> 7;
          ((float*)Cv)[(((long long)(b_*8 + hd))*512 + t_)*128 + (n & 127)] = v;
        } else if (MODE == 3) {
          float* cp = (float*)Cv + (long long)m*Ndim + n;
          *cp += v;
        } else if (MODE == 4) {
          ((u16*)Cv)[(long long)m*Ndim + n] = (u16)f2bf(gelu_f(v));
        }
      }
    }
  }
}

// ---------------- generic tiled fp32 GEMM (Wq/Wk/FAVOR/ctx/o) ----------------
// MODE: 0 plain, 2 heads store, 5 o-store (dinv scale + head merge, bf16 out)
template<int BT, int MODE>
__global__ __launch_bounds__(256)
void k_gemm(const float* __restrict__ A, const float* __restrict__ Bw,
            const float* __restrict__ bias, float* __restrict__ C,
            int Mdim, int Ndim, int Kdim,
            long long aBS, long long bBS, long long cBS, long long biasBS,
            const float* __restrict__ aux)
{
  __shared__ float As[16][128];
  __shared__ float Bs[16][128];
  const int tid = threadIdx.x;
  const int tx = tid & 15, ty = tid >> 4;
  const int m0 = blockIdx.y * 128, n0 = blockIdx.x * 128;
  const int z = blockIdx.z;
  const float* Ab = A + (long long)z * aBS;
  const float* Bb = Bw + (long long)z * bBS;
  float acc[8][8] = {};

  for (int k0 = 0; k0 < Kdim; k0 += 16) {
    #pragma unroll
    for (int l0 = 0; l0 < 512; l0 += 256) {
      const int ll = l0 + tid;
      const int r = ll >> 2, kq = (ll & 3) * 4;
      float4 v = *(const float4*)&Ab[(long long)(m0 + r) * Kdim + k0 + kq];
      As[kq+0][r] = v.x; As[kq+1][r] = v.y; As[kq+2][r] = v.z; As[kq+3][r] = v.w;
    }
    if (BT) {
      #pragma unroll
      for (int l0 = 0; l0 < 512; l0 += 256) {
        const int ll = l0 + tid;
        const int r = ll >> 2, kq = (ll & 3) * 4;
        float4 v = *(const float4*)&Bb[(long long)(n0 + r) * Kdim + k0 + kq];
        Bs[kq+0][r] = v.x; Bs[kq+1][r] = v.y; Bs[kq+2][r] = v.z; Bs[kq+3][r] = v.w;
      }
    } else {
      #pragma unroll
      for (int l0 = 0; l0 < 512; l0 += 256) {
        const int ll = l0 + tid;
        const int kr = ll >> 5, n4 = (ll & 31) * 4;
        *(float4*)&Bs[kr][n4] = *(const float4*)&Bb[(long long)(k0 + kr) * Ndim + n0 + n4];
      }
    }
    __syncthreads();
    #pragma unroll
    for (int kk = 0; kk < 16; ++kk) {
      float4 af0 = *(const float4*)&As[kk][ty*4];
      float4 af1 = *(const float4*)&As[kk][64 + ty*4];
      float4 bf0 = *(const float4*)&Bs[kk][tx*4];
      float4 bf1 = *(const float4*)&Bs[kk][64 + tx*4];
      float av[8] = {af0.x,af0.y,af0.z,af0.w,af1.x,af1.y,af1.z,af1.w};
      float bv[8] = {bf0.x,bf0.y,bf0.z,bf0.w,bf1.x,bf1.y,bf1.z,bf1.w};
      #pragma unroll
      for (int i = 0; i < 8; ++i)
        #pragma unroll
        for (int j = 0; j < 8; ++j)
          acc[i][j] = fmaf(av[i], bv[j], acc[i][j]);
    }
    __syncthreads();
  }

  float bias0[4] = {0.f,0.f,0.f,0.f}, bias1[4] = {0.f,0.f,0.f,0.f};
  if (MODE != 5 && bias != nullptr) {
    const float* bz = bias + (long long)z * biasBS;
    float4 t0 = *(const float4*)&bz[n0 + tx*4];
    float4 t1 = *(const float4*)&bz[n0 + 64 + tx*4];
    bias0[0]=t0.x; bias0[1]=t0.y; bias0[2]=t0.z; bias0[3]=t0.w;
    bias1[0]=t1.x; bias1[1]=t1.y; bias1[2]=t1.z; bias1[3]=t1.w;
  }
  float* Cz = C + (long long)z * cBS;
  #pragma unroll
  for (int i = 0; i < 8; ++i) {
    const int m = m0 + ((i < 4) ? (ty*4 + i) : (64 + ty*4 + (i - 4)));
    #pragma unroll
    for (int jb = 0; jb < 2; ++jb) {
      const int ci = n0 + (jb ? 64 : 0) + tx*4;
      float4 v;
      v.x = acc[i][jb*4+0] + (jb ? bias1[0] : bias0[0]);
      v.y = acc[i][jb*4+1] + (jb ? bias1[1] : bias0[1]);
      v.z = acc[i][jb*4+2] + (jb ? bias1[2] : bias0[2]);
      v.w = acc[i][jb*4+3] + (jb ? bias1[3] : bias0[3]);
      if (MODE == 0) {
        *(float4*)&Cz[(long long)m * Ndim + ci] = v;
      } else if (MODE == 2) {
        const int b_ = m >> 9, t_ = m & 511;
        const int hd = ci >> 7;
        *(float4*)&Cz[(((long long)(b_*8 + hd))*512 + t_)*128 + (ci & 127)] = v;
      } else if (MODE == 5) {
        const int b_ = z >> 3, hd = z & 7;
        const float sc = aux[(long long)z*512 + m];
        u16* Cb = (u16*)C;
        const long long off = ((long long)(b_*512 + m))*1024 + hd*128 + ci;
        Cb[off+0] = (u16)f2bf(v.x*sc);
        Cb[off+1] = (u16)f2bf(v.y*sc);
        Cb[off+2] = (u16)f2bf(v.z*sc);
        Cb[off+3] = (u16)f2bf(v.w*sc);
      }
    }
  }
}

// ---------------- persistent BiLSTM recurrence v3 (per-WG flags) ----------------
// grid = 32 WGs: blockIdx = dir*16 + slice. Each WG owns 32 hidden units.
// Sync: each WG publishes its h-slice then store-releases its OWN flag (64B apart);
// consumers poll 16 independent flags in parallel (no RMW serialization).
template<int OBF>
__global__ __launch_bounds__(512)
void k_lstm3(const float* __restrict__ Z, const float* __restrict__ Whh,
             float* __restrict__ outf, u16* __restrict__ outb,
             unsigned* __restrict__ hbufU, unsigned* __restrict__ flags)
{
  extern __shared__ char smem[];
  short*  Wl    = (short*)smem;              // 128*512 bf16 = 131072 B
  short*  hl    = (short*)(smem + 131072);   // 8*512 bf16  = 8192 B
  float*  gates = (float*)(smem + 139264);   // 128*8 f32   = 4096 B

  const int slice = blockIdx.x & 15, dir = blockIdx.x >> 4;
  const int tid = threadIdx.x;
  const int u0 = slice * 32;
  unsigned* selfflag = flags + dir*256 + slice*16;
  const unsigned* peer = flags + dir*256;

  // stage Whh slice -> LDS bf16 (8-elem blocks rotated by row)
  for (int blk = tid; blk < 8192; blk += 512) {
    const int lr2 = blk >> 6, bi = blk & 63;
    const long long src = ((long long)dir*2048 + (lr2>>5)*512 + u0 + (lr2&31))*512 + bi*8;
    float4 w0 = *(const float4*)&Whh[src];
    float4 w1 = *(const float4*)&Whh[src + 4];
    unsigned* dst = (unsigned*)&Wl[lr2*512 + (((bi + lr2) & 63) << 3)];
    dst[0] = f2bf(w0.x) | (f2bf(w0.y) << 16);
    dst[1] = f2bf(w0.z) | (f2bf(w0.w) << 16);
    dst[2] = f2bf(w1.x) | (f2bf(w1.y) << 16);
    dst[3] = f2bf(w1.z) | (f2bf(w1.w) << 16);
  }
  for (int i = tid; i < 2048; i += 512) ((unsigned*)hl)[i] = 0u;

  const int wv = tid >> 6, l = tid & 63;
  const int arow = wv*16 + (l & 15);
  const int bb   = l & 7;
  const int qoff = l >> 4;
  const int jj = tid >> 3, bcomb = tid & 7;
  float cst = 0.f;

  for (int s = 0; s < 512; ++s) {
    const int t = dir ? (511 - s) : s;
    float z0v = 0.f, z1v = 0.f, z2v = 0.f, z3v = 0.f;
    if (tid < 256) {
      const float* zp = Z + (((long long)dir*512 + t)*16384) + (u0 + jj)*8 + bcomb;
      z0v = zp[0]; z1v = zp[4096]; z2v = zp[8192]; z3v = zp[12288];
    }
    if (s > 0) {
      if (tid < 16) {
        const unsigned* fp = peer + tid*16;
        while (__hip_atomic_load(fp, __ATOMIC_ACQUIRE, __HIP_MEMORY_SCOPE_AGENT) < (unsigned)s) {}
      }
      __syncthreads();
      const unsigned base = ((unsigned)((s & 1)*2 + dir)) * 2048;
      #pragma unroll
      for (int q = 0; q < 4; ++q) {
        const int gidx = q*512 + tid;
        const int b = gidx >> 8, p = gidx & 255;
        unsigned v = __hip_atomic_load(&hbufU[base + b*256 + p],
                                       __ATOMIC_RELAXED, __HIP_MEMORY_SCOPE_AGENT);
        const int bi = p >> 2;
        *(unsigned*)&hl[b*512 + (((bi + b) & 63) << 3) + ((p & 3) << 1)] = v;
      }
    }
    __syncthreads();
    // gates = W @ h via mfma (two independent chains)
    f32x4 acc0 = {0.f,0.f,0.f,0.f}, acc1 = {0.f,0.f,0.f,0.f};
    #pragma unroll
    for (int ks = 0; ks < 8; ++ks) {
      const int qa = (2*ks)*4 + qoff, qb = (2*ks + 1)*4 + qoff;
      bf16x8 a0 = *(bf16x8*)&Wl[arow*512 + (((qa + arow) & 63) << 3)];
      bf16x8 b0 = *(bf16x8*)&hl[bb*512   + (((qa + bb)   & 63) << 3)];
      acc0 = __builtin_amdgcn_mfma_f32_16x16x32_bf16(a0, b0, acc0, 0, 0, 0);
      bf16x8 a1 = *(bf16x8*)&Wl[arow*512 + (((qb + arow) & 63) << 3)];
      bf16x8 b1 = *(bf16x8*)&hl[bb*512   + (((qb + bb)   & 63) << 3)];
      acc1 = __builtin_amdgcn_mfma_f32_16x16x32_bf16(a1, b1, acc1, 0, 0, 0);
    }
    const int bcol = l & 15;
    if (bcol < 8) {
      #pragma unroll
      for (int r = 0; r < 4; ++r)
        gates[(wv*16 + qoff*4 + r)*8 + bcol] = acc0[r] + acc1[r];
    }
    __syncthreads();
    unsigned hb = 0u;
    if (tid < 256) {
      const float gi = gates[jj*8        + bcomb] + z0v;
      const float gf = gates[(32+jj)*8   + bcomb] + z1v;
      const float gg = gates[(64+jj)*8   + bcomb] + z2v;
      const float go = gates[(96+jj)*8   + bcomb] + z3v;
      const float ig = 1.f/(1.f + expf(-gi));
      const float fg = 1.f/(1.f + expf(-gf));
      const float og = 1.f/(1.f + expf(-go));
      cst = fg*cst + ig*tanhf(gg);
      const float hv = og*tanhf(cst);
      hb = f2bf(hv);
      if (OBF) outb[((long long)(bcomb*512 + t))*1024 + (dir<<9) + u0 + jj] = (u16)hb;
      else     outf[((long long)(bcomb*512 + t))*1024 + (dir<<9) + u0 + jj] = hv;
    }
    const unsigned hi = (unsigned)__shfl_down((int)hb, 8, 64);
    if (tid < 256 && !(jj & 1) && s != 511) {
      const unsigned base2 = ((unsigned)(((s+1) & 1)*2 + dir)) * 2048;
      __hip_atomic_store(&hbufU[base2 + bcomb*256 + ((u0 + jj) >> 1)], hb | (hi << 16),
                         __ATOMIC_RELAXED, __HIP_MEMORY_SCOPE_AGENT);
    }
    __syncthreads();
    if (tid == 0 && s != 511) {
      __threadfence();
      __hip_atomic_store(selfflag, (unsigned)(s + 1), __ATOMIC_RELEASE, __HIP_MEMORY_SCOPE_AGENT);
    }
  }
}

// ---------------- LayerNorm: fp32 in, fp32 + bf16 out ----------------
__global__ __launch_bounds__(256)
void k_ln(const float* __restrict__ X, const float* __restrict__ gw,
          const float* __restrict__ bw, float* __restrict__ Yf, u16* __restrict__ Yb)
{
  const int row = blockIdx.x, tid = threadIdx.x;
  const float* xr = X + (long long)row * 1024;
  float4 v = *(const float4*)&xr[tid*4];
  float s  = v.x + v.y + v.z + v.w;
  float ss = v.x*v.x + v.y*v.y + v.z*v.z + v.w*v.w;
  #pragma unroll
  for (int off = 1; off < 64; off <<= 1) {
    s  += __shfl_xor(s, off, 64);
    ss += __shfl_xor(ss, off, 64);
  }
  __shared__ float rs[4], rss[4];
  const int w = tid >> 6;
  if ((tid & 63) == 0) { rs[w] = s; rss[w] = ss; }
  __syncthreads();
  s  = rs[0] + rs[1] + rs[2] + rs[3];
  ss = rss[0] + rss[1] + rss[2] + rss[3];
  const float mu = s * (1.f/1024.f);
  const float var = ss * (1.f/1024.f) - mu*mu;
  const float rstd = rsqrtf(var + 1e-5f);
  float4 g4 = *(const float4*)&gw[tid*4];
  float4 b4 = *(const float4*)&bw[tid*4];
  float4 o;
  o.x = (v.x - mu)*rstd*g4.x + b4.x;
  o.y = (v.y - mu)*rstd*g4.y + b4.y;
  o.z = (v.z - mu)*rstd*g4.z + b4.z;
  o.w = (v.w - mu)*rstd*g4.w + b4.w;
  *(float4*)&Yf[(long long)row*1024 + tid*4] = o;
  ushort4 ob; ob.x=(u16)f2bf(o.x); ob.y=(u16)f2bf(o.y); ob.z=(u16)f2bf(o.z); ob.w=(u16)f2bf(o.w);
  *(ushort4*)&Yb[(long long)row*1024 + tid*4] = ob;
}

// ---------------- FAVOR helpers ----------------
__global__ void k_diag(const float* __restrict__ X, float* __restrict__ dout)
{
  const int tid = threadIdx.x;
  const int row = blockIdx.x*4 + (tid >> 6);
  const int lane = tid & 63;
  float2 v = *(const float2*)&X[(long long)row*128 + lane*2];
  float ss = v.x*v.x + v.y*v.y;
  #pragma unroll
  for (int off = 1; off < 64; off <<= 1) ss += __shfl_xor(ss, off, 64);
  if (lane == 0) dout[row] = ss * 0.044194173824159216f; // 0.5 * dn^2
}

__global__ void k_favq(float* __restrict__ dd, const float* __restrict__ diag)
{
  const int tid = threadIdx.x;
  const int row = blockIdx.x*4 + (tid >> 6);
  const int lane = tid & 63;
  float4 v = *(const float4*)&dd[(long long)row*256 + lane*4];
  float mx = fmaxf(fmaxf(v.x, v.y), fmaxf(v.z, v.w));
  #pragma unroll
  for (int off = 1; off < 64; off <<= 1) mx = fmaxf(mx, __shfl_xor(mx, off, 64));
  const float dg = diag[row];
  float4 o;
  o.x = (expf(v.x - dg - mx) + KEPS)*0.0625f;
  o.y = (expf(v.y - dg - mx) + KEPS)*0.0625f;
  o.z = (expf(v.z - dg - mx) + KEPS)*0.0625f;
  o.w = (expf(v.w - dg - mx) + KEPS)*0.0625f;
  *(float4*)&dd[(long long)row*256 + lane*4] = o;
}

__global__ __launch_bounds__(256)
void k_kmax(const float* __restrict__ dd, float* __restrict__ kmx)
{
  const int bh = blockIdx.x, tid = threadIdx.x;
  const float* p = dd + (long long)bh * 131072;
  float mx = -3.4e38f;
  for (int i = tid*4; i < 131072; i += 1024) {
    float4 v = *(const float4*)&p[i];
    mx = fmaxf(mx, fmaxf(fmaxf(v.x, v.y), fmaxf(v.z, v.w)));
  }
  #pragma unroll
  for (int off = 1; off < 64; off <<= 1) mx = fmaxf(mx, __shfl_xor(mx, off, 64));
  __shared__ float red[4];
  if ((tid & 63) == 0) red[tid >> 6] = mx;
  __syncthreads();
  if (tid == 0) kmx[bh] = fmaxf(fmaxf(red[0], red[1]), fmaxf(red[2], red[3]));
}

__global__ void k_fkT(const float* __restrict__ dd, const float* __restrict__ diag,
                      const float* __restrict__ kmx, float* __restrict__ kT)
{
  __shared__ float tile[32][33];
  const int bh = blockIdx.z;
  const int t0 = blockIdx.x * 32, m0 = blockIdx.y * 32;
  const int tx = threadIdx.x, ty = threadIdx.y;
  const float km = kmx[bh];
  #pragma unroll
  for (int j = 0; j < 4; ++j) {
    const int t = t0 + ty + j*8;
    const float v = dd[((long long)bh*512 + t)*256 + m0 + tx];
    tile[ty + j*8][tx] = (expf(v - diag[bh*512 + t] - km) + KEPS) * 0.0625f;
  }
  __syncthreads();
  #pragma unroll
  for (int j = 0; j < 4; ++j) {
    const int m = m0 + ty + j*8;
    kT[((long long)bh*256 + m)*512 + t0 + tx] = tile[tx][ty + j*8];
  }
}

__global__ void k_ksum(const float* __restrict__ kT, float* __restrict__ ksum)
{
  const int tid = threadIdx.x;
  const int row = blockIdx.x*4 + (tid >> 6);
  const int lane = tid & 63;
  float4 a = *(const float4*)&kT[(long long)row*512 + lane*8];
  float4 b = *(const float4*)&kT[(long long)row*512 + lane*8 + 4];
  float s = a.x+a.y+a.z+a.w + b.x+b.y+b.z+b.w;
  #pragma unroll
  for (int off = 1; off < 64; off <<= 1) s += __shfl_xor(s, off, 64);
  if (lane == 0) ksum[row] = s;
}

__global__ void k_dinv(const float* __restrict__ qp, const float* __restrict__ ksum,
                       float* __restrict__ dinv)
{
  const int tid = threadIdx.x;
  const int row = blockIdx.x*4 + (tid >> 6);
  const int lane = tid & 63;
  const int bh = row >> 9;
  float4 q = *(const float4*)&qp[(long long)row*256 + lane*4];
  float4 k = *(const float4*)&ksum[bh*256 + lane*4];
  float s = q.x*k.x + q.y*k.y + q.z*k.z + q.w*k.w;
  #pragma unroll
  for (int off = 1; off < 64; off <<= 1) s += __shfl_xor(s, off, 64);
  if (lane == 0) dinv[row] = 1.f / s;
}

// ---------------- pooling + classifier ----------------
__global__ void k_pool(const float* __restrict__ h, float* __restrict__ pooled)
{
  const int idx = blockIdx.x * 256 + threadIdx.x; // 8192
  const int b = idx >> 10, d = idx & 1023;
  const float* p = h + (long long)b * 524288 + d;
  float s0=0,s1=0,s2=0,s3=0;
  for (int t0 = 0; t0 < 512; t0 += 4) {
    s0 += p[(long long)(t0+0)*1024];
    s1 += p[(long long)(t0+1)*1024];
    s2 += p[(long long)(t0+2)*1024];
    s3 += p[(long long)(t0+3)*1024];
  }
  pooled[idx] = (s0+s1+s2+s3) * (1.f/512.f);
}

__global__ __launch_bounds__(256)
void k_cls(const float* __restrict__ pooled, const float* __restrict__ W1,
           const float* __restrict__ b1, const float* __restrict__ W2,
           const float* __restrict__ b2, float* __restrict__ out)
{
  const int b = blockIdx.x, tid = threadIdx.x;
  __shared__ float pl[1024];
  __shared__ float hd[512];
  *(float4*)&pl[tid*4] = *(const float4*)&pooled[b*1024 + tid*4];
  __syncthreads();
  for (int u = tid; u < 512; u += 256) {
    float acc = b1[u];
    for (int k = 0; k < 1024; ++k) acc = fmaf(pl[k], W1[(long long)k*512 + u], acc);
    hd[u] = fmaxf(acc, 0.f);
  }
  __syncthreads();
  if (tid < 2) {
    float acc = b2[tid];
    for (int k = 0; k < 512; ++k) acc = fmaf(hd[k], W2[k*2 + tid], acc);
    out[b*2 + tid] = acc;
  }
}

// ---------------- host ----------------
static void* symp(const void* s) { void* p = nullptr; (void)hipGetSymbolAddress(&p, s); return p; }

extern "C" void kernel_launch(void* const* d_in, const int* in_sizes, int n_in,
                              void* d_out, int out_size, void* d_ws, size_t ws_size,
                              hipStream_t stream)
{
  (void)in_sizes; (void)n_in; (void)d_ws; (void)ws_size; (void)out_size;
  const float* x     = (const float*)d_in[0];
  const float* l0Wih = (const float*)d_in[1];
  const float* l0Whh = (const float*)d_in[2];
  const float* l0bih = (const float*)d_in[3];
  const float* l0bhh = (const float*)d_in[4];
  const float* l1Wih = (const float*)d_in[5];
  const float* l1Whh = (const float*)d_in[6];
  const float* l1bih = (const float*)d_in[7];
  const float* l1bhh = (const float*)d_in[8];
  const float* proj  = (const float*)d_in[9];
  const float* ln1g  = (const float*)d_in[10];
  const float* ln1b  = (const float*)d_in[11];
  const float* Wq    = (const float*)d_in[12];
  const float* Wk    = (const float*)d_in[13];
  const float* Wv    = (const float*)d_in[14];
  const float* Wo    = (const float*)d_in[15];
  const float* bq    = (const float*)d_in[16];
  const float* bk    = (const float*)d_in[17];
  const float* bv    = (const float*)d_in[18];
  const float* bo    = (const float*)d_in[19];
  const float* ln2g  = (const float*)d_in[20];
  const float* ln2b  = (const float*)d_in[21];
  const float* Wf1   = (const float*)d_in[22];
  const float* bf1   = (const float*)d_in[23];
  const float* Wf2   = (const float*)d_in[24];
  const float* bf2   = (const float*)d_in[25];
  const float* cW1   = (const float*)d_in[26];
  const float* cb1   = (const float*)d_in[27];
  const float* cW2   = (const float*)d_in[28];
  const float* cb2   = (const float*)d_in[29];

  float* z0    = (float*)symp(HIP_SYMBOL(g_z0));
  float* z1    = (float*)symp(HIP_SYMBOL(g_z1));
  float* hres  = (float*)symp(HIP_SYMBOL(g_hres));
  float* y     = (float*)symp(HIP_SYMBOL(g_y));
  float* qlin  = (float*)symp(HIP_SYMBOL(g_qlin));
  float* klin  = (float*)symp(HIP_SYMBOL(g_klin));
  float* vlin  = (float*)symp(HIP_SYMBOL(g_vlin));
  float* qp    = (float*)symp(HIP_SYMBOL(g_qp));
  float* ddb   = (float*)symp(HIP_SYMBOL(g_ddb));
  float* kT    = (float*)symp(HIP_SYMBOL(g_kT));
  float* ctx   = (float*)symp(HIP_SYMBOL(g_ctx));
  float* bs0   = (float*)symp(HIP_SYMBOL(g_bs0));
  float* bs1   = (float*)symp(HIP_SYMBOL(g_bs1));
  float* projs = (float*)symp(HIP_SYMBOL(g_projs));
  float* diagq = (float*)symp(HIP_SYMBOL(g_diagq));
  float* diagk = (float*)symp(HIP_SYMBOL(g_diagk));
  float* kmx   = (float*)symp(HIP_SYMBOL(g_kmx));
  float* ksum  = (float*)symp(HIP_SYMBOL(g_ksum));
  float* dinv  = (float*)symp(HIP_SYMBOL(g_dinv));
  unsigned* hbuf = (unsigned*)symp(HIP_SYMBOL(g_hbuf));
  float* pooled= (float*)symp(HIP_SYMBOL(g_pooled));
  unsigned* flags = (unsigned*)symp(HIP_SYMBOL(g_flags));
  u16* xbf   = (u16*)symp(HIP_SYMBOL(g_xbf));
  u16* x1bf  = (u16*)symp(HIP_SYMBOL(g_x1bf));
  u16* ybf   = (u16*)symp(HIP_SYMBOL(g_ybf));
  u16* obufbf= (u16*)symp(HIP_SYMBOL(g_obufbf));
  u16* ffbbf = (u16*)symp(HIP_SYMBOL(g_ffbbf));
  u16* wih0b = (u16*)symp(HIP_SYMBOL(g_wih0b));
  u16* wih1b = (u16*)symp(HIP_SYMBOL(g_wih1b));
  u16* wvt   = (u16*)symp(HIP_SYMBOL(g_wvt));
  u16* wot   = (u16*)symp(HIP_SYMBOL(g_wot));
  u16* wf1t  = (u16*)symp(HIP_SYMBOL(g_wf1t));
  u16* wf2t  = (u16*)symp(HIP_SYMBOL(g_wf2t));

  const float dn = 0.29730177875068026f; // 128^-0.25
  const int LSTM_LDS = 143360;
  (void)hipFuncSetAttribute((const void*)k_lstm3<1>,
                            hipFuncAttributeMaxDynamicSharedMemorySize, LSTM_LDS);
  (void)hipFuncSetAttribute((const void*)k_lstm3<0>,
                            hipFuncAttributeMaxDynamicSharedMemorySize, LSTM_LDS);

  k_zero<<<4, 256, 0, stream>>>((int*)flags);
  k_add2<<<16, 256, 0, stream>>>(bs0, l0bih, l0bhh, 4096);
  k_add2<<<16, 256, 0, stream>>>(bs1, l1bih, l1bhh, 4096);
  k_scale<<<128, 256, 0, stream>>>(projs, proj, dn, 32768);

  // convert inputs/weights to bf16
  k_cvt<<<1024, 256, 0, stream>>>(x, xbf, 262144);
  k_cvt<<<1024, 256, 0, stream>>>(l0Wih, wih0b, 262144);
  k_cvt<<<4096, 256, 0, stream>>>(l1Wih, wih1b, 1048576);
  k_w2bfT<<<dim3(32,32,2),  dim3(32,8), 0, stream>>>(Wv,  wvt,  1024, 1024, 1048576LL, 1048576LL);
  k_w2bfT<<<dim3(32,32,2),  dim3(32,8), 0, stream>>>(Wo,  wot,  1024, 1024, 1048576LL, 1048576LL);
  k_w2bfT<<<dim3(128,32,2), dim3(32,8), 0, stream>>>(Wf1, wf1t, 1024, 4096, 4194304LL, 4194304LL);
  k_w2bfT<<<dim3(32,128,2), dim3(32,8), 0, stream>>>(Wf2, wf2t, 4096, 1024, 4194304LL, 4194304LL);

  // LSTM layer 0
  k_bgemm<1><<<dim3(16,32,2), 256, 0, stream>>>(xbf, wih0b, bs0, z0,
      2048, 256, 0LL, 524288LL, 8388608LL, 2048LL);
  k_lstm3<1><<<32, 512, LSTM_LDS, stream>>>(z0, l0Whh, nullptr, x1bf, hbuf, flags);
  // LSTM layer 1
  k_bgemm<1><<<dim3(16,32,2), 256, 0, stream>>>(x1bf, wih1b, bs1, z1,
      2048, 1024, 0LL, 2097152LL, 8388608LL, 2048LL);
  k_lstm3<0><<<32, 512, LSTM_LDS, stream>>>(z1, l1Whh, hres, nullptr, hbuf, flags + 512);

  for (int i = 0; i < 2; ++i) {
    const long long wOff = (long long)i * 1048576;
    // pre-norm attention
    k_ln<<<4096, 256, 0, stream>>>(hres, ln1g + i*1024, ln1b + i*1024, y, ybf);
    k_gemm<0,2><<<dim3(8,32,1), 256, 0, stream>>>(y, Wq + wOff, bq + i*1024, qlin,
        4096, 1024, 1024, 0LL, 0LL, 0LL, 0LL, nullptr);
    k_gemm<0,2><<<dim3(8,32,1), 256, 0, stream>>>(y, Wk + wOff, bk + i*1024, klin,
        4096, 1024, 1024, 0LL, 0LL, 0LL, 0LL, nullptr);
    k_bgemm<2><<<dim3(8,32,1), 256, 0, stream>>>(ybf, wvt + wOff, bv + i*1024, vlin,
        1024, 1024, 0LL, 0LL, 0LL, 0LL);
    k_diag<<<8192, 256, 0, stream>>>(qlin, diagq);
    k_diag<<<8192, 256, 0, stream>>>(klin, diagk);
    // FAVOR q
    k_gemm<1,0><<<dim3(2,256,1), 256, 0, stream>>>(qlin, projs, nullptr, qp,
        32768, 256, 128, 0LL, 0LL, 0LL, 0LL, nullptr);
    k_favq<<<8192, 256, 0, stream>>>(qp, diagq);
    // FAVOR k
    k_gemm<1,0><<<dim3(2,256,1), 256, 0, stream>>>(klin, projs, nullptr, ddb,
        32768, 256, 128, 0LL, 0LL, 0LL, 0LL, nullptr);
    k_kmax<<<64, 256, 0, stream>>>(ddb, kmx);
    k_fkT<<<dim3(16,8,64), dim3(32,8), 0, stream>>>(ddb, diagk, kmx, kT);
    k_ksum<<<4096, 256, 0, stream>>>(kT, ksum);
    // ctx = k'^T @ v
    k_gemm<0,0><<<dim3(1,2,64), 256, 0, stream>>>(kT, vlin, nullptr, ctx,
        256, 128, 512, 131072LL, 65536LL, 32768LL, 0LL, nullptr);
    k_dinv<<<8192, 256, 0, stream>>>(qp, ksum, dinv);
    // o = (q' @ ctx) * dinv -> bf16 merged heads
    k_gemm<0,5><<<dim3(1,4,64), 256, 0, stream>>>(qp, ctx, nullptr, (float*)obufbf,
        512, 128, 256, 131072LL, 32768LL, 0LL, 0LL, dinv);
    // output projection + residual
    k_bgemm<3><<<dim3(8,32,1), 256, 0, stream>>>(obufbf, wot + wOff, bo + i*1024, hres,
        1024, 1024, 0LL, 0LL, 0LL, 0LL);
    // pre-norm FF
    k_ln<<<4096, 256, 0, stream>>>(hres, ln2g + i*1024, ln2b + i*1024, y, ybf);
    k_bgemm<4><<<dim3(32,32,1), 256, 0, stream>>>(ybf, wf1t + (long long)i*4194304,
        bf1 + i*4096, ffbbf, 4096, 1024, 0LL, 0LL, 0LL, 0LL);
    k_bgemm<3><<<dim3(8,32,1), 256, 0, stream>>>(ffbbf, wf2t + (long long)i*4194304,
        bf2 + i*1024, hres, 1024, 4096, 0LL, 0LL, 0LL, 0LL);
  }

  k_pool<<<32, 256, 0, stream>>>(hres, pooled);
  k_cls<<<8, 256, 0, stream>>>(pooled, cW1, cb1, cW2, cb2, (float*)d_out);
}

// Round 5
// 4621.173 us; speedup vs baseline: 6.0503x; 1.5060x over previous
//
#include <hip/hip_runtime.h>

#define KEPS 1e-4f

typedef __attribute__((ext_vector_type(8))) short bf16x8;
typedef __attribute__((ext_vector_type(4))) float f32x4;
typedef __attribute__((ext_vector_type(4))) unsigned u32x4;
typedef unsigned short u16;

// ---------------- static device workspace ----------------
__device__ float g_z0[2u*512*2048*8];     // layer0 input-proj Z [dir][t][4H][b]
__device__ float g_z1[2u*512*2048*8];
__device__ float g_hres[8u*512*1024];     // residual stream [B,T,D] fp32
__device__ float g_qlin[8u*8*512*128];    // [B,H,T,DH] fp32 (for diag)
__device__ float g_klin[8u*8*512*128];
__device__ float g_vlin[8u*8*512*128];
__device__ float g_qp[8u*8*512*256];      // q' [B,H,T,M]
__device__ float g_ddb[8u*8*512*256];
__device__ float g_kT[8u*8*256*512];      // k'^T [B,H,M,T]
__device__ float g_ctx[64u*256*128];      // [BH,M,DH]
__device__ float g_bs0[2*2048];
__device__ float g_bs1[2*2048];
__device__ float g_diagq[32768];
__device__ float g_diagk[32768];
__device__ float g_kmx[64];
__device__ float g_ksum[64*256];
__device__ float g_dinv[32768];
__device__ __align__(16) unsigned g_hbuf[2*2*8*256]; // h exchange [slot][dir][b][256 u32]
__device__ float g_pooled[8*1024];
__device__ unsigned g_flags[1024];        // [layer][dir][slice] flags, 64B padded

// bf16 buffers
__device__ u16 g_xbf[8u*512*256];
__device__ u16 g_x1bf[8u*512*1024];
__device__ u16 g_ybf[8u*512*1024];        // LN out hi
__device__ u16 g_ylo[8u*512*1024];        // LN out lo
__device__ u16 g_obufbf[8u*512*1024];
__device__ u16 g_ffbbf[8u*512*4096];
__device__ u16 g_qhi[8u*8*512*128];
__device__ u16 g_qlo2[8u*8*512*128];
__device__ u16 g_khi[8u*8*512*128];
__device__ u16 g_klo2[8u*8*512*128];
__device__ u16 g_wih0b[2u*2048*256];
__device__ u16 g_wih1b[2u*2048*1024];
__device__ u16 g_wvt[2u*1024*1024];       // [layer][N=out][K=in]
__device__ u16 g_wot[2u*1024*1024];
__device__ u16 g_wf1t[2u*4096*1024];
__device__ u16 g_wf2t[2u*1024*4096];
__device__ u16 g_wqth[2u*1024*1024];
__device__ u16 g_wqtl[2u*1024*1024];
__device__ u16 g_wkth[2u*1024*1024];
__device__ u16 g_wktl[2u*1024*1024];
__device__ u16 g_projh[256*128];
__device__ u16 g_projl[256*128];

// ---------------- helpers ----------------
__device__ __forceinline__ float gelu_f(float x) {
  return 0.5f * x * (1.f + erff(x * 0.70710678118654752f));
}
__device__ __forceinline__ unsigned f2bf(float f) {
  unsigned x = __float_as_uint(f);
  return (x + 0x7FFFu + ((x >> 16) & 1u)) >> 16;   // RNE
}
__device__ __forceinline__ float bf2f(unsigned h) {
  return __uint_as_float(h << 16);
}
// agent-coherent (cross-XCD) 16B load/store: sc1 = agent scope
__device__ __forceinline__ u32x4 ld16_sc1(const unsigned* p) {
  u32x4 v;
  asm volatile("global_load_dwordx4 %0, %1, off sc1\n\ts_waitcnt vmcnt(0)"
               : "=v"(v) : "v"(p) : "memory");
  return v;
}
__device__ __forceinline__ void st16_sc1(unsigned* p, u32x4 v) {
  asm volatile("global_store_dwordx4 %0, %1, off sc1" :: "v"(p), "v"(v) : "memory");
}
__device__ __forceinline__ void st4_sc1(unsigned* p, unsigned v) {
  asm volatile("global_store_dword %0, %1, off sc1" :: "v"(p), "v"(v) : "memory");
}

__global__ void k_zero(int* p) { p[blockIdx.x*256 + threadIdx.x] = 0; }

__global__ void k_add2(float* __restrict__ dst, const float* __restrict__ a,
                       const float* __restrict__ b, int n) {
  int i = blockIdx.x * 256 + threadIdx.x;
  if (i < n) dst[i] = a[i] + b[i];
}
__global__ void k_cvt(const float* __restrict__ src, u16* __restrict__ dst, int n4) {
  int i = blockIdx.x * 256 + threadIdx.x;
  if (i < n4) {
    float4 v = ((const float4*)src)[i];
    ushort4 o; o.x=(u16)f2bf(v.x); o.y=(u16)f2bf(v.y); o.z=(u16)f2bf(v.z); o.w=(u16)f2bf(v.w);
    ((ushort4*)dst)[i] = o;
  }
}
__global__ void k_scale_split(const float* __restrict__ a, u16* __restrict__ dh,
                              u16* __restrict__ dl, float s, int n) {
  int i = blockIdx.x*256 + threadIdx.x;
  if (i < n) {
    float v = a[i]*s;
    unsigned h = f2bf(v);
    dh[i] = (u16)h; dl[i] = (u16)f2bf(v - bf2f(h));
  }
}
// fp32 [K][N] -> bf16 [N][K]
__global__ void k_w2bfT(const float* __restrict__ src, u16* __restrict__ dst,
                        int K, int N, long long sBS, long long dBS)
{
  __shared__ float tile[32][33];
  const int z = blockIdx.z;
  const int n0 = blockIdx.x*32, k0 = blockIdx.y*32;
  const int tx = threadIdx.x, ty = threadIdx.y;
  const float* s = src + (long long)z*sBS;
  u16* d = dst + (long long)z*dBS;
  #pragma unroll
  for (int j = 0; j < 4; ++j)
    tile[ty + j*8][tx] = s[(long long)(k0 + ty + j*8)*N + n0 + tx];
  __syncthreads();
  #pragma unroll
  for (int j = 0; j < 4; ++j)
    d[(long long)(n0 + ty + j*8)*K + k0 + tx] = (u16)f2bf(tile[tx][ty + j*8]);
}
// fp32 [K][N] -> bf16 hi/lo [N][K]
__global__ void k_w2bfT_split(const float* __restrict__ src, u16* __restrict__ dh,
                              u16* __restrict__ dl, int K, int N,
                              long long sBS, long long dBS)
{
  __shared__ float tile[32][33];
  const int z = blockIdx.z;
  const int n0 = blockIdx.x*32, k0 = blockIdx.y*32;
  const int tx = threadIdx.x, ty = threadIdx.y;
  const float* s = src + (long long)z*sBS;
  #pragma unroll
  for (int j = 0; j < 4; ++j)
    tile[ty + j*8][tx] = s[(long long)(k0 + ty + j*8)*N + n0 + tx];
  __syncthreads();
  #pragma unroll
  for (int j = 0; j < 4; ++j) {
    const float v = tile[tx][ty + j*8];
    const unsigned h = f2bf(v);
    const long long off = (long long)z*dBS + (long long)(n0 + ty + j*8)*K + k0 + tx;
    dh[off] = (u16)h; dl[off] = (u16)f2bf(v - bf2f(h));
  }
}

// ---------------- bf16 MFMA GEMM ----------------
// C[M,N] = A[M,K](bf16) @ B[N,K](bf16)^T + bias
// MODE: 0 plain f32, 1 Z-scatter f32 [t][4H][b], 2 heads f32 [B,H,T,DH],
//       3 add-into f32 C, 4 GELU -> bf16
template<int MODE>
__global__ __launch_bounds__(256)
void k_bgemm(const u16* __restrict__ A, const u16* __restrict__ Bw,
             const float* __restrict__ bias, void* __restrict__ Cv,
             int Ndim, int Kdim,
             long long aBS, long long bBS, long long cBS, long long biasBS)
{
  __shared__ __align__(16) u16 As[128*40];
  __shared__ __align__(16) u16 Bs[128*40];
  const int tid = threadIdx.x;
  const int m0 = blockIdx.y * 128, n0 = blockIdx.x * 128, z = blockIdx.z;
  const u16* Ab = A + (long long)z*aBS;
  const u16* Bb = Bw + (long long)z*bBS;
  const int wv = tid >> 6, l = tid & 63;
  const int wm = wv >> 1, wn = wv & 1;
  const int lr = l & 15, lk = l >> 4;
  const int str = tid >> 2, stc = (tid & 3)*8;
  f32x4 acc[4][4];
  #pragma unroll
  for (int i=0;i<4;++i)
    #pragma unroll
    for (int j=0;j<4;++j) acc[i][j] = (f32x4){0.f,0.f,0.f,0.f};

  for (int k0 = 0; k0 < Kdim; k0 += 32) {
    #pragma unroll
    for (int q = 0; q < 2; ++q) {
      const int r = q*64 + str;
      *(uint4*)&As[r*40 + stc] = *(const uint4*)&Ab[(long long)(m0 + r)*Kdim + k0 + stc];
      *(uint4*)&Bs[r*40 + stc] = *(const uint4*)&Bb[(long long)(n0 + r)*Kdim + k0 + stc];
    }
    __syncthreads();
    bf16x8 af[4], bfr[4];
    #pragma unroll
    for (int i=0;i<4;++i) af[i]  = *(bf16x8*)&As[(wm*64 + i*16 + lr)*40 + lk*8];
    #pragma unroll
    for (int j=0;j<4;++j) bfr[j] = *(bf16x8*)&Bs[(wn*64 + j*16 + lr)*40 + lk*8];
    #pragma unroll
    for (int i=0;i<4;++i)
      #pragma unroll
      for (int j=0;j<4;++j)
        acc[i][j] = __builtin_amdgcn_mfma_f32_16x16x32_bf16(af[i], bfr[j], acc[i][j], 0, 0, 0);
    __syncthreads();
  }

  #pragma unroll
  for (int j=0;j<4;++j) {
    const int n = n0 + wn*64 + j*16 + lr;
    const float bvv = bias ? bias[(long long)z*biasBS + n] : 0.f;
    #pragma unroll
    for (int i=0;i<4;++i) {
      #pragma unroll
      for (int r=0;r<4;++r) {
        const int m = m0 + wm*64 + i*16 + lk*4 + r;
        float v = acc[i][j][r] + bvv;
        if (MODE == 0) {
          ((float*)Cv)[(long long)z*cBS + (long long)m*Ndim + n] = v;
        } else if (MODE == 1) {
          const int b_ = m >> 9, t_ = m & 511;
          ((float*)Cv)[(long long)z*cBS + ((long long)t_*2048 + n)*8 + b_] = v;
        } else if (MODE == 2) {
          const int b_ = m >> 9, t_ = m & 511;
          const int hd = n >> 7;
          ((float*)Cv)[(((long long)(b_*8 + hd))*512 + t_)*128 + (n & 127)] = v;
        } else if (MODE == 3) {
          float* cp = (float*)Cv + (long long)m*Ndim + n;
          *cp += v;
        } else if (MODE == 4) {
          ((u16*)Cv)[(long long)m*Ndim + n] = (u16)f2bf(gelu_f(v));
        }
      }
    }
  }
}

// ---------------- bf16x2 split (3-MFMA, ~fp32 accurate) GEMM ----------------
// C[M,N] = A[M,K] @ B[N,K]^T + bias, A/B given as hi/lo bf16 planes.
// MODE: 0 plain f32 out; 2 heads store f32 + bf16 hi/lo split planes
template<int MODE>
__global__ __launch_bounds__(256)
void k_b3gemm(const u16* __restrict__ Ah, const u16* __restrict__ Al,
              const u16* __restrict__ Bh, const u16* __restrict__ Bl,
              const float* __restrict__ bias, float* __restrict__ Cf,
              u16* __restrict__ Chi, u16* __restrict__ Clo,
              int Ndim, int Kdim)
{
  __shared__ __align__(16) u16 Ash[128*40];
  __shared__ __align__(16) u16 Asl[128*40];
  __shared__ __align__(16) u16 Bsh[128*40];
  __shared__ __align__(16) u16 Bsl[128*40];
  const int tid = threadIdx.x;
  const int m0 = blockIdx.y * 128, n0 = blockIdx.x * 128;
  const int wv = tid >> 6, l = tid & 63;
  const int wm = wv >> 1, wn = wv & 1;
  const int lr = l & 15, lk = l >> 4;
  const int str = tid >> 2, stc = (tid & 3)*8;
  f32x4 acc[4][4];
  #pragma unroll
  for (int i=0;i<4;++i)
    #pragma unroll
    for (int j=0;j<4;++j) acc[i][j] = (f32x4){0.f,0.f,0.f,0.f};

  for (int k0 = 0; k0 < Kdim; k0 += 32) {
    #pragma unroll
    for (int q = 0; q < 2; ++q) {
      const int r = q*64 + str;
      const long long ao = (long long)(m0 + r)*Kdim + k0 + stc;
      const long long bo = (long long)(n0 + r)*Kdim + k0 + stc;
      *(uint4*)&Ash[r*40 + stc] = *(const uint4*)&Ah[ao];
      *(uint4*)&Asl[r*40 + stc] = *(const uint4*)&Al[ao];
      *(uint4*)&Bsh[r*40 + stc] = *(const uint4*)&Bh[bo];
      *(uint4*)&Bsl[r*40 + stc] = *(const uint4*)&Bl[bo];
    }
    __syncthreads();
    bf16x8 ah[4], al_[4], bh[4], bl_[4];
    #pragma unroll
    for (int i=0;i<4;++i) {
      ah[i]  = *(bf16x8*)&Ash[(wm*64 + i*16 + lr)*40 + lk*8];
      al_[i] = *(bf16x8*)&Asl[(wm*64 + i*16 + lr)*40 + lk*8];
    }
    #pragma unroll
    for (int j=0;j<4;++j) {
      bh[j]  = *(bf16x8*)&Bsh[(wn*64 + j*16 + lr)*40 + lk*8];
      bl_[j] = *(bf16x8*)&Bsl[(wn*64 + j*16 + lr)*40 + lk*8];
    }
    #pragma unroll
    for (int i=0;i<4;++i)
      #pragma unroll
      for (int j=0;j<4;++j) {
        acc[i][j] = __builtin_amdgcn_mfma_f32_16x16x32_bf16(ah[i],  bh[j],  acc[i][j], 0, 0, 0);
        acc[i][j] = __builtin_amdgcn_mfma_f32_16x16x32_bf16(ah[i],  bl_[j], acc[i][j], 0, 0, 0);
        acc[i][j] = __builtin_amdgcn_mfma_f32_16x16x32_bf16(al_[i], bh[j],  acc[i][j], 0, 0, 0);
      }
    __syncthreads();
  }

  #pragma unroll
  for (int j=0;j<4;++j) {
    const int n = n0 + wn*64 + j*16 + lr;
    const float bvv = bias ? bias[n] : 0.f;
    #pragma unroll
    for (int i=0;i<4;++i) {
      #pragma unroll
      for (int r=0;r<4;++r) {
        const int m = m0 + wm*64 + i*16 + lk*4 + r;
        float v = acc[i][j][r] + bvv;
        if (MODE == 0) {
          Cf[(long long)m*Ndim + n] = v;
        } else if (MODE == 2) {
          const int b_ = m >> 9, t_ = m & 511;
          const int hd = n >> 7;
          const long long off = (((long long)(b_*8 + hd))*512 + t_)*128 + (n & 127);
          Cf[off] = v;
          const unsigned h = f2bf(v);
          Chi[off] = (u16)h;
          Clo[off] = (u16)f2bf(v - bf2f(h));
        }
      }
    }
  }
}

// ---------------- generic tiled fp32 GEMM (ctx / o) ----------------
// MODE: 0 plain, 5 o-store (dinv scale + head merge, bf16 out)
template<int BT, int MODE>
__global__ __launch_bounds__(256)
void k_gemm(const float* __restrict__ A, const float* __restrict__ Bw,
            const float* __restrict__ bias, float* __restrict__ C,
            int Mdim, int Ndim, int Kdim,
            long long aBS, long long bBS, long long cBS, long long biasBS,
            const float* __restrict__ aux)
{
  __shared__ float As[16][128];
  __shared__ float Bs[16][128];
  const int tid = threadIdx.x;
  const int tx = tid & 15, ty = tid >> 4;
  const int m0 = blockIdx.y * 128, n0 = blockIdx.x * 128;
  const int z = blockIdx.z;
  const float* Ab = A + (long long)z * aBS;
  const float* Bb = Bw + (long long)z * bBS;
  float acc[8][8] = {};

  for (int k0 = 0; k0 < Kdim; k0 += 16) {
    #pragma unroll
    for (int l0 = 0; l0 < 512; l0 += 256) {
      const int ll = l0 + tid;
      const int r = ll >> 2, kq = (ll & 3) * 4;
      float4 v = *(const float4*)&Ab[(long long)(m0 + r) * Kdim + k0 + kq];
      As[kq+0][r] = v.x; As[kq+1][r] = v.y; As[kq+2][r] = v.z; As[kq+3][r] = v.w;
    }
    if (BT) {
      #pragma unroll
      for (int l0 = 0; l0 < 512; l0 += 256) {
        const int ll = l0 + tid;
        const int r = ll >> 2, kq = (ll & 3) * 4;
        float4 v = *(const float4*)&Bb[(long long)(n0 + r) * Kdim + k0 + kq];
        Bs[kq+0][r] = v.x; Bs[kq+1][r] = v.y; Bs[kq+2][r] = v.z; Bs[kq+3][r] = v.w;
      }
    } else {
      #pragma unroll
      for (int l0 = 0; l0 < 512; l0 += 256) {
        const int ll = l0 + tid;
        const int kr = ll >> 5, n4 = (ll & 31) * 4;
        *(float4*)&Bs[kr][n4] = *(const float4*)&Bb[(long long)(k0 + kr) * Ndim + n0 + n4];
      }
    }
    __syncthreads();
    #pragma unroll
    for (int kk = 0; kk < 16; ++kk) {
      float4 af0 = *(const float4*)&As[kk][ty*4];
      float4 af1 = *(const float4*)&As[kk][64 + ty*4];
      float4 bf0 = *(const float4*)&Bs[kk][tx*4];
      float4 bf1 = *(const float4*)&Bs[kk][64 + tx*4];
      float av[8] = {af0.x,af0.y,af0.z,af0.w,af1.x,af1.y,af1.z,af1.w};
      float bv[8] = {bf0.x,bf0.y,bf0.z,bf0.w,bf1.x,bf1.y,bf1.z,bf1.w};
      #pragma unroll
      for (int i = 0; i < 8; ++i)
        #pragma unroll
        for (int j = 0; j < 8; ++j)
          acc[i][j] = fmaf(av[i], bv[j], acc[i][j]);
    }
    __syncthreads();
  }

  float* Cz = C + (long long)z * cBS;
  #pragma unroll
  for (int i = 0; i < 8; ++i) {
    const int m = m0 + ((i < 4) ? (ty*4 + i) : (64 + ty*4 + (i - 4)));
    #pragma unroll
    for (int jb = 0; jb < 2; ++jb) {
      const int ci = n0 + (jb ? 64 : 0) + tx*4;
      float4 v;
      v.x = acc[i][jb*4+0]; v.y = acc[i][jb*4+1];
      v.z = acc[i][jb*4+2]; v.w = acc[i][jb*4+3];
      if (MODE == 0) {
        *(float4*)&Cz[(long long)m * Ndim + ci] = v;
      } else if (MODE == 5) {
        const int b_ = z >> 3, hd = z & 7;
        const float sc = aux[(long long)z*512 + m];
        u16* Cb = (u16*)C;
        const long long off = ((long long)(b_*512 + m))*1024 + hd*128 + ci;
        Cb[off+0] = (u16)f2bf(v.x*sc);
        Cb[off+1] = (u16)f2bf(v.y*sc);
        Cb[off+2] = (u16)f2bf(v.z*sc);
        Cb[off+3] = (u16)f2bf(v.w*sc);
      }
    }
  }
}

// ---------------- persistent BiLSTM recurrence v4 (sc1-only hot loop) ----------
// grid = 32 WGs: blockIdx = dir*16 + slice. Each WG owns 32 hidden units.
// All cross-WG traffic is explicit sc1 (agent-coherent) 16B transactions; ordering
// via __syncthreads()'s vmcnt(0) drain. No threadfence / acquire-release lowering.
template<int OBF>
__global__ __launch_bounds__(512)
void k_lstm4(const float* __restrict__ Z, const float* __restrict__ Whh,
             float* __restrict__ outf, u16* __restrict__ outb,
             unsigned* __restrict__ hbufU, unsigned* __restrict__ flags)
{
  extern __shared__ char smem[];
  short*          Wl    = (short*)smem;              // 128*512 bf16 = 131072 B
  short*          hl    = (short*)(smem + 131072);   // 8*512 bf16  = 8192 B
  float*          gates = (float*)(smem + 139264);   // 128*8 f32   = 4096 B
  unsigned short* houts = (unsigned short*)(smem + 143360); // 8*32 u16 = 512 B

  const int slice = blockIdx.x & 15, dir = blockIdx.x >> 4;
  const int tid = threadIdx.x;
  const int u0 = slice * 32;
  unsigned* selfflag = flags + dir*256 + slice*16;
  const unsigned* peer = flags + dir*256;

  // stage Whh slice -> LDS bf16 (8-elem blocks rotated by row)
  for (int blk = tid; blk < 8192; blk += 512) {
    const int lr2 = blk >> 6, bi = blk & 63;
    const long long src = ((long long)dir*2048 + (lr2>>5)*512 + u0 + (lr2&31))*512 + bi*8;
    float4 w0 = *(const float4*)&Whh[src];
    float4 w1 = *(const float4*)&Whh[src + 4];
    unsigned* dst = (unsigned*)&Wl[lr2*512 + (((bi + lr2) & 63) << 3)];
    dst[0] = f2bf(w0.x) | (f2bf(w0.y) << 16);
    dst[1] = f2bf(w0.z) | (f2bf(w0.w) << 16);
    dst[2] = f2bf(w1.x) | (f2bf(w1.y) << 16);
    dst[3] = f2bf(w1.z) | (f2bf(w1.w) << 16);
  }
  for (int i = tid; i < 2048; i += 512) ((unsigned*)hl)[i] = 0u;

  const int wv = tid >> 6, l = tid & 63;
  const int arow = wv*16 + (l & 15);
  const int bb   = l & 7;
  const int qoff = l >> 4;
  const int jj = tid >> 3, bcomb = tid & 7;
  float cst = 0.f;

  for (int s = 0; s < 512; ++s) {
    const int t = dir ? (511 - s) : s;
    // early-issue Z loads (fp32, layout [dir][t][row][b]); coalesced
    float z0v = 0.f, z1v = 0.f, z2v = 0.f, z3v = 0.f;
    if (tid < 256) {
      const float* zp = Z + (((long long)dir*512 + t)*16384) + (u0 + jj)*8 + bcomb;
      z0v = zp[0]; z1v = zp[4096]; z2v = zp[8192]; z3v = zp[12288];
    }
    if (s > 0) {
      // poll peer flags (relaxed agent loads)
      if (tid < 16) {
        const unsigned* fp = peer + tid*16;
        while (__hip_atomic_load(fp, __ATOMIC_RELAXED, __HIP_MEMORY_SCOPE_AGENT) < (unsigned)s) {}
      }
      __syncthreads();
      // gather h: one 16B sc1 load per thread, scatter to bank-rotated LDS
      const unsigned base = ((unsigned)((s & 1)*2 + dir)) * 2048;
      u32x4 v = ld16_sc1(&hbufU[base + tid*4]);
      const int b = tid >> 6, q = tid & 63;
      *(u32x4*)((char*)hl + b*1024 + (((q + b) & 63) << 4)) = v;
    }
    __syncthreads();
    // gates = W @ h via mfma (two independent chains)
    f32x4 acc0 = {0.f,0.f,0.f,0.f}, acc1 = {0.f,0.f,0.f,0.f};
    #pragma unroll
    for (int ks = 0; ks < 8; ++ks) {
      const int qa = (2*ks)*4 + qoff, qb = (2*ks + 1)*4 + qoff;
      bf16x8 a0 = *(bf16x8*)&Wl[arow*512 + (((qa + arow) & 63) << 3)];
      bf16x8 b0 = *(bf16x8*)&hl[bb*512   + (((qa + bb)   & 63) << 3)];
      acc0 = __builtin_amdgcn_mfma_f32_16x16x32_bf16(a0, b0, acc0, 0, 0, 0);
      bf16x8 a1 = *(bf16x8*)&Wl[arow*512 + (((qb + arow) & 63) << 3)];
      bf16x8 b1 = *(bf16x8*)&hl[bb*512   + (((qb + bb)   & 63) << 3)];
      acc1 = __builtin_amdgcn_mfma_f32_16x16x32_bf16(a1, b1, acc1, 0, 0, 0);
    }
    const int bcol = l & 15;
    if (bcol < 8) {
      #pragma unroll
      for (int r = 0; r < 4; ++r)
        gates[(wv*16 + qoff*4 + r)*8 + bcol] = acc0[r] + acc1[r];
    }
    __syncthreads();
    if (tid < 256) {
      const float gi = gates[jj*8        + bcomb] + z0v;
      const float gf = gates[(32+jj)*8   + bcomb] + z1v;
      const float gg = gates[(64+jj)*8   + bcomb] + z2v;
      const float go = gates[(96+jj)*8   + bcomb] + z3v;
      const float ig = 1.f/(1.f + expf(-gi));
      const float fg = 1.f/(1.f + expf(-gf));
      const float og = 1.f/(1.f + expf(-go));
      cst = fg*cst + ig*tanhf(gg);
      const float hv = og*tanhf(cst);
      const unsigned hb = f2bf(hv);
      if (OBF) outb[((long long)(bcomb*512 + t))*1024 + (dir<<9) + u0 + jj] = (u16)hb;
      else     outf[((long long)(bcomb*512 + t))*1024 + (dir<<9) + u0 + jj] = hv;
      houts[bcomb*32 + jj] = (unsigned short)hb;
    }
    __syncthreads();
    if (s != 511) {
      // publish: 32 threads x 16B sc1 stores
      if (tid < 32) {
        const int b = tid >> 2, q4 = tid & 3;
        u32x4 v = *(const u32x4*)&houts[b*32 + q4*8];
        const unsigned base2 = ((unsigned)(((s+1) & 1)*2 + dir)) * 2048;
        st16_sc1(&hbufU[base2 + b*256 + (u0 >> 1) + q4*4], v);
      }
      __syncthreads();  // vmcnt(0) drain: publishes are at coherence point
      if (tid == 0) st4_sc1(selfflag, (unsigned)(s + 1));
    }
  }
}

// ---------------- LayerNorm: fp32 in, bf16 hi+lo out ----------------
__global__ __launch_bounds__(256)
void k_ln(const float* __restrict__ X, const float* __restrict__ gw,
          const float* __restrict__ bw, u16* __restrict__ Yh, u16* __restrict__ Yl)
{
  const int row = blockIdx.x, tid = threadIdx.x;
  const float* xr = X + (long long)row * 1024;
  float4 v = *(const float4*)&xr[tid*4];
  float s  = v.x + v.y + v.z + v.w;
  float ss = v.x*v.x + v.y*v.y + v.z*v.z + v.w*v.w;
  #pragma unroll
  for (int off = 1; off < 64; off <<= 1) {
    s  += __shfl_xor(s, off, 64);
    ss += __shfl_xor(ss, off, 64);
  }
  __shared__ float rs[4], rss[4];
  const int w = tid >> 6;
  if ((tid & 63) == 0) { rs[w] = s; rss[w] = ss; }
  __syncthreads();
  s  = rs[0] + rs[1] + rs[2] + rs[3];
  ss = rss[0] + rss[1] + rss[2] + rss[3];
  const float mu = s * (1.f/1024.f);
  const float var = ss * (1.f/1024.f) - mu*mu;
  const float rstd = rsqrtf(var + 1e-5f);
  float4 g4 = *(const float4*)&gw[tid*4];
  float4 b4 = *(const float4*)&bw[tid*4];
  float4 o;
  o.x = (v.x - mu)*rstd*g4.x + b4.x;
  o.y = (v.y - mu)*rstd*g4.y + b4.y;
  o.z = (v.z - mu)*rstd*g4.z + b4.z;
  o.w = (v.w - mu)*rstd*g4.w + b4.w;
  ushort4 hh, ll;
  hh.x=(u16)f2bf(o.x); ll.x=(u16)f2bf(o.x - bf2f(f2bf(o.x)));
  hh.y=(u16)f2bf(o.y); ll.y=(u16)f2bf(o.y - bf2f(f2bf(o.y)));
  hh.z=(u16)f2bf(o.z); ll.z=(u16)f2bf(o.z - bf2f(f2bf(o.z)));
  hh.w=(u16)f2bf(o.w); ll.w=(u16)f2bf(o.w - bf2f(f2bf(o.w)));
  *(ushort4*)&Yh[(long long)row*1024 + tid*4] = hh;
  *(ushort4*)&Yl[(long long)row*1024 + tid*4] = ll;
}

// ---------------- FAVOR helpers ----------------
__global__ void k_diag(const float* __restrict__ X, float* __restrict__ dout)
{
  const int tid = threadIdx.x;
  const int row = blockIdx.x*4 + (tid >> 6);
  const int lane = tid & 63;
  float2 v = *(const float2*)&X[(long long)row*128 + lane*2];
  float ss = v.x*v.x + v.y*v.y;
  #pragma unroll
  for (int off = 1; off < 64; off <<= 1) ss += __shfl_xor(ss, off, 64);
  if (lane == 0) dout[row] = ss * 0.044194173824159216f; // 0.5 * dn^2
}

__global__ void k_favq(float* __restrict__ dd, const float* __restrict__ diag)
{
  const int tid = threadIdx.x;
  const int row = blockIdx.x*4 + (tid >> 6);
  const int lane = tid & 63;
  float4 v = *(const float4*)&dd[(long long)row*256 + lane*4];
  float mx = fmaxf(fmaxf(v.x, v.y), fmaxf(v.z, v.w));
  #pragma unroll
  for (int off = 1; off < 64; off <<= 1) mx = fmaxf(mx, __shfl_xor(mx, off, 64));
  const float dg = diag[row];
  float4 o;
  o.x = (expf(v.x - dg - mx) + KEPS)*0.0625f;
  o.y = (expf(v.y - dg - mx) + KEPS)*0.0625f;
  o.z = (expf(v.z - dg - mx) + KEPS)*0.0625f;
  o.w = (expf(v.w - dg - mx) + KEPS)*0.0625f;
  *(float4*)&dd[(long long)row*256 + lane*4] = o;
}

__global__ __launch_bounds__(256)
void k_kmax(const float* __restrict__ dd, float* __restrict__ kmx)
{
  const int bh = blockIdx.x, tid = threadIdx.x;
  const float* p = dd + (long long)bh * 131072;
  float mx = -3.4e38f;
  for (int i = tid*4; i < 131072; i += 1024) {
    float4 v = *(const float4*)&p[i];
    mx = fmaxf(mx, fmaxf(fmaxf(v.x, v.y), fmaxf(v.z, v.w)));
  }
  #pragma unroll
  for (int off = 1; off < 64; off <<= 1) mx = fmaxf(mx, __shfl_xor(mx, off, 64));
  __shared__ float red[4];
  if ((tid & 63) == 0) red[tid >> 6] = mx;
  __syncthreads();
  if (tid == 0) kmx[bh] = fmaxf(fmaxf(red[0], red[1]), fmaxf(red[2], red[3]));
}

__global__ void k_fkT(const float* __restrict__ dd, const float* __restrict__ diag,
                      const float* __restrict__ kmx, float* __restrict__ kT)
{
  __shared__ float tile[32][33];
  const int bh = blockIdx.z;
  const int t0 = blockIdx.x * 32, m0 = blockIdx.y * 32;
  const int tx = threadIdx.x, ty = threadIdx.y;
  const float km = kmx[bh];
  #pragma unroll
  for (int j = 0; j < 4; ++j) {
    const int t = t0 + ty + j*8;
    const float v = dd[((long long)bh*512 + t)*256 + m0 + tx];
    tile[ty + j*8][tx] = (expf(v - diag[bh*512 + t] - km) + KEPS) * 0.0625f;
  }
  __syncthreads();
  #pragma unroll
  for (int j = 0; j < 4; ++j) {
    const int m = m0 + ty + j*8;
    kT[((long long)bh*256 + m)*512 + t0 + tx] = tile[tx][ty + j*8];
  }
}

__global__ void k_ksum(const float* __restrict__ kT, float* __restrict__ ksum)
{
  const int tid = threadIdx.x;
  const int row = blockIdx.x*4 + (tid >> 6);
  const int lane = tid & 63;
  float4 a = *(const float4*)&kT[(long long)row*512 + lane*8];
  float4 b = *(const float4*)&kT[(long long)row*512 + lane*8 + 4];
  float s = a.x+a.y+a.z+a.w + b.x+b.y+b.z+b.w;
  #pragma unroll
  for (int off = 1; off < 64; off <<= 1) s += __shfl_xor(s, off, 64);
  if (lane == 0) ksum[row] = s;
}

__global__ void k_dinv(const float* __restrict__ qp, const float* __restrict__ ksum,
                       float* __restrict__ dinv)
{
  const int tid = threadIdx.x;
  const int row = blockIdx.x*4 + (tid >> 6);
  const int lane = tid & 63;
  const int bh = row >> 9;
  float4 q = *(const float4*)&qp[(long long)row*256 + lane*4];
  float4 k = *(const float4*)&ksum[bh*256 + lane*4];
  float s = q.x*k.x + q.y*k.y + q.z*k.z + q.w*k.w;
  #pragma unroll
  for (int off = 1; off < 64; off <<= 1) s += __shfl_xor(s, off, 64);
  if (lane == 0) dinv[row] = 1.f / s;
}

// ---------------- pooling + classifier ----------------
__global__ void k_pool(const float* __restrict__ h, float* __restrict__ pooled)
{
  const int idx = blockIdx.x * 256 + threadIdx.x; // 8192
  const int b = idx >> 10, d = idx & 1023;
  const float* p = h + (long long)b * 524288 + d;
  float s0=0,s1=0,s2=0,s3=0;
  for (int t0 = 0; t0 < 512; t0 += 4) {
    s0 += p[(long long)(t0+0)*1024];
    s1 += p[(long long)(t0+1)*1024];
    s2 += p[(long long)(t0+2)*1024];
    s3 += p[(long long)(t0+3)*1024];
  }
  pooled[idx] = (s0+s1+s2+s3) * (1.f/512.f);
}

__global__ __launch_bounds__(256)
void k_cls(const float* __restrict__ pooled, const float* __restrict__ W1,
           const float* __restrict__ b1, const float* __restrict__ W2,
           const float* __restrict__ b2, float* __restrict__ out)
{
  const int b = blockIdx.x, tid = threadIdx.x;
  __shared__ float pl[1024];
  __shared__ float hd[512];
  *(float4*)&pl[tid*4] = *(const float4*)&pooled[b*1024 + tid*4];
  __syncthreads();
  for (int u = tid; u < 512; u += 256) {
    float acc = b1[u];
    for (int k = 0; k < 1024; ++k) acc = fmaf(pl[k], W1[(long long)k*512 + u], acc);
    hd[u] = fmaxf(acc, 0.f);
  }
  __syncthreads();
  if (tid < 2) {
    float acc = b2[tid];
    for (int k = 0; k < 512; ++k) acc = fmaf(hd[k], W2[k*2 + tid], acc);
    out[b*2 + tid] = acc;
  }
}

// ---------------- host ----------------
static void* symp(const void* s) { void* p = nullptr; (void)hipGetSymbolAddress(&p, s); return p; }

extern "C" void kernel_launch(void* const* d_in, const int* in_sizes, int n_in,
                              void* d_out, int out_size, void* d_ws, size_t ws_size,
                              hipStream_t stream)
{
  (void)in_sizes; (void)n_in; (void)d_ws; (void)ws_size; (void)out_size;
  const float* x     = (const float*)d_in[0];
  const float* l0Wih = (const float*)d_in[1];
  const float* l0Whh = (const float*)d_in[2];
  const float* l0bih = (const float*)d_in[3];
  const float* l0bhh = (const float*)d_in[4];
  const float* l1Wih = (const float*)d_in[5];
  const float* l1Whh = (const float*)d_in[6];
  const float* l1bih = (const float*)d_in[7];
  const float* l1bhh = (const float*)d_in[8];
  const float* proj  = (const float*)d_in[9];
  const float* ln1g  = (const float*)d_in[10];
  const float* ln1b  = (const float*)d_in[11];
  const float* Wq    = (const float*)d_in[12];
  const float* Wk    = (const float*)d_in[13];
  const float* Wv    = (const float*)d_in[14];
  const float* Wo    = (const float*)d_in[15];
  const float* bq    = (const float*)d_in[16];
  const float* bk    = (const float*)d_in[17];
  const float* bv    = (const float*)d_in[18];
  const float* bo    = (const float*)d_in[19];
  const float* ln2g  = (const float*)d_in[20];
  const float* ln2b  = (const float*)d_in[21];
  const float* Wf1   = (const float*)d_in[22];
  const float* bf1   = (const float*)d_in[23];
  const float* Wf2   = (const float*)d_in[24];
  const float* bf2   = (const float*)d_in[25];
  const float* cW1   = (const float*)d_in[26];
  const float* cb1   = (const float*)d_in[27];
  const float* cW2   = (const float*)d_in[28];
  const float* cb2   = (const float*)d_in[29];

  float* z0    = (float*)symp(HIP_SYMBOL(g_z0));
  float* z1    = (float*)symp(HIP_SYMBOL(g_z1));
  float* hres  = (float*)symp(HIP_SYMBOL(g_hres));
  float* qlin  = (float*)symp(HIP_SYMBOL(g_qlin));
  float* klin  = (float*)symp(HIP_SYMBOL(g_klin));
  float* vlin  = (float*)symp(HIP_SYMBOL(g_vlin));
  float* qp    = (float*)symp(HIP_SYMBOL(g_qp));
  float* ddb   = (float*)symp(HIP_SYMBOL(g_ddb));
  float* kT    = (float*)symp(HIP_SYMBOL(g_kT));
  float* ctx   = (float*)symp(HIP_SYMBOL(g_ctx));
  float* bs0   = (float*)symp(HIP_SYMBOL(g_bs0));
  float* bs1   = (float*)symp(HIP_SYMBOL(g_bs1));
  float* diagq = (float*)symp(HIP_SYMBOL(g_diagq));
  float* diagk = (float*)symp(HIP_SYMBOL(g_diagk));
  float* kmx   = (float*)symp(HIP_SYMBOL(g_kmx));
  float* ksum  = (float*)symp(HIP_SYMBOL(g_ksum));
  float* dinv  = (float*)symp(HIP_SYMBOL(g_dinv));
  unsigned* hbuf = (unsigned*)symp(HIP_SYMBOL(g_hbuf));
  float* pooled= (float*)symp(HIP_SYMBOL(g_pooled));
  unsigned* flags = (unsigned*)symp(HIP_SYMBOL(g_flags));
  u16* xbf   = (u16*)symp(HIP_SYMBOL(g_xbf));
  u16* x1bf  = (u16*)symp(HIP_SYMBOL(g_x1bf));
  u16* ybf   = (u16*)symp(HIP_SYMBOL(g_ybf));
  u16* ylo   = (u16*)symp(HIP_SYMBOL(g_ylo));
  u16* obufbf= (u16*)symp(HIP_SYMBOL(g_obufbf));
  u16* ffbbf = (u16*)symp(HIP_SYMBOL(g_ffbbf));
  u16* qhi   = (u16*)symp(HIP_SYMBOL(g_qhi));
  u16* qlo2  = (u16*)symp(HIP_SYMBOL(g_qlo2));
  u16* khi   = (u16*)symp(HIP_SYMBOL(g_khi));
  u16* klo2  = (u16*)symp(HIP_SYMBOL(g_klo2));
  u16* wih0b = (u16*)symp(HIP_SYMBOL(g_wih0b));
  u16* wih1b = (u16*)symp(HIP_SYMBOL(g_wih1b));
  u16* wvt   = (u16*)symp(HIP_SYMBOL(g_wvt));
  u16* wot   = (u16*)symp(HIP_SYMBOL(g_wot));
  u16* wf1t  = (u16*)symp(HIP_SYMBOL(g_wf1t));
  u16* wf2t  = (u16*)symp(HIP_SYMBOL(g_wf2t));
  u16* wqth  = (u16*)symp(HIP_SYMBOL(g_wqth));
  u16* wqtl  = (u16*)symp(HIP_SYMBOL(g_wqtl));
  u16* wkth  = (u16*)symp(HIP_SYMBOL(g_wkth));
  u16* wktl  = (u16*)symp(HIP_SYMBOL(g_wktl));
  u16* projh = (u16*)symp(HIP_SYMBOL(g_projh));
  u16* projl = (u16*)symp(HIP_SYMBOL(g_projl));

  const float dn = 0.29730177875068026f; // 128^-0.25
  const int LSTM_LDS = 143872;
  (void)hipFuncSetAttribute((const void*)k_lstm4<1>,
                            hipFuncAttributeMaxDynamicSharedMemorySize, LSTM_LDS);
  (void)hipFuncSetAttribute((const void*)k_lstm4<0>,
                            hipFuncAttributeMaxDynamicSharedMemorySize, LSTM_LDS);

  k_zero<<<4, 256, 0, stream>>>((int*)flags);
  k_add2<<<16, 256, 0, stream>>>(bs0, l0bih, l0bhh, 4096);
  k_add2<<<16, 256, 0, stream>>>(bs1, l1bih, l1bhh, 4096);
  k_scale_split<<<128, 256, 0, stream>>>(proj, projh, projl, dn, 32768);

  // convert inputs/weights to bf16
  k_cvt<<<1024, 256, 0, stream>>>(x, xbf, 262144);
  k_cvt<<<1024, 256, 0, stream>>>(l0Wih, wih0b, 262144);
  k_cvt<<<4096, 256, 0, stream>>>(l1Wih, wih1b, 1048576);
  k_w2bfT<<<dim3(32,32,2),  dim3(32,8), 0, stream>>>(Wv,  wvt,  1024, 1024, 1048576LL, 1048576LL);
  k_w2bfT<<<dim3(32,32,2),  dim3(32,8), 0, stream>>>(Wo,  wot,  1024, 1024, 1048576LL, 1048576LL);
  k_w2bfT<<<dim3(128,32,2), dim3(32,8), 0, stream>>>(Wf1, wf1t, 1024, 4096, 4194304LL, 4194304LL);
  k_w2bfT<<<dim3(32,128,2), dim3(32,8), 0, stream>>>(Wf2, wf2t, 4096, 1024, 4194304LL, 4194304LL);
  k_w2bfT_split<<<dim3(32,32,2), dim3(32,8), 0, stream>>>(Wq, wqth, wqtl, 1024, 1024, 1048576LL, 1048576LL);
  k_w2bfT_split<<<dim3(32,32,2), dim3(32,8), 0, stream>>>(Wk, wkth, wktl, 1024, 1024, 1048576LL, 1048576LL);

  // LSTM layer 0
  k_bgemm<1><<<dim3(16,32,2), 256, 0, stream>>>(xbf, wih0b, bs0, z0,
      2048, 256, 0LL, 524288LL, 8388608LL, 2048LL);
  k_lstm4<1><<<32, 512, LSTM_LDS, stream>>>(z0, l0Whh, nullptr, x1bf, hbuf, flags);
  // LSTM layer 1
  k_bgemm<1><<<dim3(16,32,2), 256, 0, stream>>>(x1bf, wih1b, bs1, z1,
      2048, 1024, 0LL, 2097152LL, 8388608LL, 2048LL);
  k_lstm4<0><<<32, 512, LSTM_LDS, stream>>>(z1, l1Whh, hres, nullptr, hbuf, flags + 512);

  for (int i = 0; i < 2; ++i) {
    const long long wOffU = (long long)i * 1048576;
    // pre-norm attention
    k_ln<<<4096, 256, 0, stream>>>(hres, ln1g + i*1024, ln1b + i*1024, ybf, ylo);
    k_b3gemm<2><<<dim3(8,32,1), 256, 0, stream>>>(ybf, ylo, wqth + wOffU, wqtl + wOffU,
        bq + i*1024, qlin, qhi, qlo2, 1024, 1024);
    k_b3gemm<2><<<dim3(8,32,1), 256, 0, stream>>>(ybf, ylo, wkth + wOffU, wktl + wOffU,
        bk + i*1024, klin, khi, klo2, 1024, 1024);
    k_bgemm<2><<<dim3(8,32,1), 256, 0, stream>>>(ybf, wvt + wOffU, bv + i*1024, vlin,
        1024, 1024, 0LL, 0LL, 0LL, 0LL);
    k_diag<<<8192, 256, 0, stream>>>(qlin, diagq);
    k_diag<<<8192, 256, 0, stream>>>(klin, diagk);
    // FAVOR q
    k_b3gemm<0><<<dim3(2,256,1), 256, 0, stream>>>(qhi, qlo2, projh, projl,
        nullptr, qp, nullptr, nullptr, 256, 128);
    k_favq<<<8192, 256, 0, stream>>>(qp, diagq);
    // FAVOR k
    k_b3gemm<0><<<dim3(2,256,1), 256, 0, stream>>>(khi, klo2, projh, projl,
        nullptr, ddb, nullptr, nullptr, 256, 128);
    k_kmax<<<64, 256, 0, stream>>>(ddb, kmx);
    k_fkT<<<dim3(16,8,64), dim3(32,8), 0, stream>>>(ddb, diagk, kmx, kT);
    k_ksum<<<4096, 256, 0, stream>>>(kT, ksum);
    // ctx = k'^T @ v
    k_gemm<0,0><<<dim3(1,2,64), 256, 0, stream>>>(kT, vlin, nullptr, ctx,
        256, 128, 512, 131072LL, 65536LL, 32768LL, 0LL, nullptr);
    k_dinv<<<8192, 256, 0, stream>>>(qp, ksum, dinv);
    // o = (q' @ ctx) * dinv -> bf16 merged heads
    k_gemm<0,5><<<dim3(1,4,64), 256, 0, stream>>>(qp, ctx, nullptr, (float*)obufbf,
        512, 128, 256, 131072LL, 32768LL, 0LL, 0LL, dinv);
    // output projection + residual
    k_bgemm<3><<<dim3(8,32,1), 256, 0, stream>>>(obufbf, wot + wOffU, bo + i*1024, hres,
        1024, 1024, 0LL, 0LL, 0LL, 0LL);
    // pre-norm FF
    k_ln<<<4096, 256, 0, stream>>>(hres, ln2g + i*1024, ln2b + i*1024, ybf, ylo);
    k_bgemm<4><<<dim3(32,32,1), 256, 0, stream>>>(ybf, wf1t + (long long)i*4194304,
        bf1 + i*4096, ffbbf, 4096, 1024, 0LL, 0LL, 0LL, 0LL);
    k_bgemm<3><<<dim3(8,32,1), 256, 0, stream>>>(ffbbf, wf2t + (long long)i*4194304,
        bf2 + i*1024, hres, 1024, 4096, 0LL, 0LL, 0LL, 0LL);
  }

  k_pool<<<32, 256, 0, stream>>>(hres, pooled);
  k_cls<<<8, 256, 0, stream>>>(pooled, cW1, cb1, cW2, cb2, (float*)d_out);
}

// Round 6
// 4361.928 us; speedup vs baseline: 6.4099x; 1.0594x over previous
//
#include <hip/hip_runtime.h>

#define KEPS 1e-4f

typedef __attribute__((ext_vector_type(8))) short bf16x8;
typedef __attribute__((ext_vector_type(4))) float f32x4;
typedef __attribute__((ext_vector_type(4))) unsigned u32x4;
typedef unsigned short u16;

// ---------------- static device workspace ----------------
__device__ float g_z0[2u*512*2048*8];     // layer0 input-proj Z [dir][t][4H][b]
__device__ float g_z1[2u*512*2048*8];
__device__ float g_hres[8u*512*1024];     // residual stream [B,T,D] fp32
__device__ float g_qlin[8u*8*512*128];    // [B,H,T,DH] fp32 (for diag)
__device__ float g_klin[8u*8*512*128];
__device__ float g_vlin[8u*8*512*128];
__device__ float g_qp[8u*8*512*256];      // q' [B,H,T,M]
__device__ float g_ddb[8u*8*512*256];
__device__ float g_kT[8u*8*256*512];      // k'^T [B,H,M,T]
__device__ float g_ctx[64u*256*128];      // [BH,M,DH]
__device__ float g_bs0[2*2048];
__device__ float g_bs1[2*2048];
__device__ float g_diagq[32768];
__device__ float g_diagk[32768];
__device__ float g_kmx[64];
__device__ float g_ksum[64*256];
__device__ float g_dinv[32768];
__device__ __align__(16) unsigned g_hbuf[2*2*8*256]; // h exchange [slot][dir][b][256 u32]
__device__ float g_pooled[8*1024];

// bf16 buffers
__device__ u16 g_xbf[8u*512*256];
__device__ u16 g_x1bf[8u*512*1024];
__device__ u16 g_ybf[8u*512*1024];        // LN out hi
__device__ u16 g_ylo[8u*512*1024];        // LN out lo
__device__ u16 g_obufbf[8u*512*1024];
__device__ u16 g_ffbbf[8u*512*4096];
__device__ u16 g_qhi[8u*8*512*128];
__device__ u16 g_qlo2[8u*8*512*128];
__device__ u16 g_khi[8u*8*512*128];
__device__ u16 g_klo2[8u*8*512*128];
__device__ u16 g_wih0b[2u*2048*256];
__device__ u16 g_wih1b[2u*2048*1024];
__device__ u16 g_wvt[2u*1024*1024];       // [layer][N=out][K=in]
__device__ u16 g_wot[2u*1024*1024];
__device__ u16 g_wf1t[2u*4096*1024];
__device__ u16 g_wf2t[2u*1024*4096];
__device__ u16 g_wqth[2u*1024*1024];
__device__ u16 g_wqtl[2u*1024*1024];
__device__ u16 g_wkth[2u*1024*1024];
__device__ u16 g_wktl[2u*1024*1024];
__device__ u16 g_projh[256*128];
__device__ u16 g_projl[256*128];

// ---------------- helpers ----------------
__device__ __forceinline__ float gelu_f(float x) {
  return 0.5f * x * (1.f + erff(x * 0.70710678118654752f));
}
__device__ __forceinline__ unsigned f2bf(float f) {
  unsigned x = __float_as_uint(f);
  return (x + 0x7FFFu + ((x >> 16) & 1u)) >> 16;   // RNE
}
__device__ __forceinline__ float bf2f(unsigned h) {
  return __uint_as_float(h << 16);
}
// agent-coherent (cross-XCD) 16B load/store: sc1 = agent scope
__device__ __forceinline__ u32x4 ld16_sc1(const unsigned* p) {
  u32x4 v;
  asm volatile("global_load_dwordx4 %0, %1, off sc1\n\ts_waitcnt vmcnt(0)"
               : "=v"(v) : "v"(p) : "memory");
  return v;
}
__device__ __forceinline__ void st16_sc1(unsigned* p, u32x4 v) {
  asm volatile("global_store_dwordx4 %0, %1, off sc1" :: "v"(p), "v"(v) : "memory");
}

__global__ void k_add2(float* __restrict__ dst, const float* __restrict__ a,
                       const float* __restrict__ b, int n) {
  int i = blockIdx.x * 256 + threadIdx.x;
  if (i < n) dst[i] = a[i] + b[i];
}
__global__ void k_cvt(const float* __restrict__ src, u16* __restrict__ dst, int n4) {
  int i = blockIdx.x * 256 + threadIdx.x;
  if (i < n4) {
    float4 v = ((const float4*)src)[i];
    ushort4 o; o.x=(u16)f2bf(v.x); o.y=(u16)f2bf(v.y); o.z=(u16)f2bf(v.z); o.w=(u16)f2bf(v.w);
    ((ushort4*)dst)[i] = o;
  }
}
__global__ void k_scale_split(const float* __restrict__ a, u16* __restrict__ dh,
                              u16* __restrict__ dl, float s, int n) {
  int i = blockIdx.x*256 + threadIdx.x;
  if (i < n) {
    float v = a[i]*s;
    unsigned h = f2bf(v);
    dh[i] = (u16)h; dl[i] = (u16)f2bf(v - bf2f(h));
  }
}
// fp32 [K][N] -> bf16 [N][K]
__global__ void k_w2bfT(const float* __restrict__ src, u16* __restrict__ dst,
                        int K, int N, long long sBS, long long dBS)
{
  __shared__ float tile[32][33];
  const int z = blockIdx.z;
  const int n0 = blockIdx.x*32, k0 = blockIdx.y*32;
  const int tx = threadIdx.x, ty = threadIdx.y;
  const float* s = src + (long long)z*sBS;
  u16* d = dst + (long long)z*dBS;
  #pragma unroll
  for (int j = 0; j < 4; ++j)
    tile[ty + j*8][tx] = s[(long long)(k0 + ty + j*8)*N + n0 + tx];
  __syncthreads();
  #pragma unroll
  for (int j = 0; j < 4; ++j)
    d[(long long)(n0 + ty + j*8)*K + k0 + tx] = (u16)f2bf(tile[tx][ty + j*8]);
}
// fp32 [K][N] -> bf16 hi/lo [N][K]
__global__ void k_w2bfT_split(const float* __restrict__ src, u16* __restrict__ dh,
                              u16* __restrict__ dl, int K, int N,
                              long long sBS, long long dBS)
{
  __shared__ float tile[32][33];
  const int z = blockIdx.z;
  const int n0 = blockIdx.x*32, k0 = blockIdx.y*32;
  const int tx = threadIdx.x, ty = threadIdx.y;
  const float* s = src + (long long)z*sBS;
  #pragma unroll
  for (int j = 0; j < 4; ++j)
    tile[ty + j*8][tx] = s[(long long)(k0 + ty + j*8)*N + n0 + tx];
  __syncthreads();
  #pragma unroll
  for (int j = 0; j < 4; ++j) {
    const float v = tile[tx][ty + j*8];
    const unsigned h = f2bf(v);
    const long long off = (long long)z*dBS + (long long)(n0 + ty + j*8)*K + k0 + tx;
    dh[off] = (u16)h; dl[off] = (u16)f2bf(v - bf2f(h));
  }
}

// ---------------- bf16 MFMA GEMM ----------------
// C[M,N] = A[M,K](bf16) @ B[N,K](bf16)^T + bias
// MODE: 0 plain f32, 1 Z-scatter f32 [t][4H][b], 2 heads f32 [B,H,T,DH],
//       3 add-into f32 C, 4 GELU -> bf16
template<int MODE>
__global__ __launch_bounds__(256)
void k_bgemm(const u16* __restrict__ A, const u16* __restrict__ Bw,
             const float* __restrict__ bias, void* __restrict__ Cv,
             int Ndim, int Kdim,
             long long aBS, long long bBS, long long cBS, long long biasBS)
{
  __shared__ __align__(16) u16 As[128*40];
  __shared__ __align__(16) u16 Bs[128*40];
  const int tid = threadIdx.x;
  const int m0 = blockIdx.y * 128, n0 = blockIdx.x * 128, z = blockIdx.z;
  const u16* Ab = A + (long long)z*aBS;
  const u16* Bb = Bw + (long long)z*bBS;
  const int wv = tid >> 6, l = tid & 63;
  const int wm = wv >> 1, wn = wv & 1;
  const int lr = l & 15, lk = l >> 4;
  const int str = tid >> 2, stc = (tid & 3)*8;
  f32x4 acc[4][4];
  #pragma unroll
  for (int i=0;i<4;++i)
    #pragma unroll
    for (int j=0;j<4;++j) acc[i][j] = (f32x4){0.f,0.f,0.f,0.f};

  for (int k0 = 0; k0 < Kdim; k0 += 32) {
    #pragma unroll
    for (int q = 0; q < 2; ++q) {
      const int r = q*64 + str;
      *(uint4*)&As[r*40 + stc] = *(const uint4*)&Ab[(long long)(m0 + r)*Kdim + k0 + stc];
      *(uint4*)&Bs[r*40 + stc] = *(const uint4*)&Bb[(long long)(n0 + r)*Kdim + k0 + stc];
    }
    __syncthreads();
    bf16x8 af[4], bfr[4];
    #pragma unroll
    for (int i=0;i<4;++i) af[i]  = *(bf16x8*)&As[(wm*64 + i*16 + lr)*40 + lk*8];
    #pragma unroll
    for (int j=0;j<4;++j) bfr[j] = *(bf16x8*)&Bs[(wn*64 + j*16 + lr)*40 + lk*8];
    #pragma unroll
    for (int i=0;i<4;++i)
      #pragma unroll
      for (int j=0;j<4;++j)
        acc[i][j] = __builtin_amdgcn_mfma_f32_16x16x32_bf16(af[i], bfr[j], acc[i][j], 0, 0, 0);
    __syncthreads();
  }

  #pragma unroll
  for (int j=0;j<4;++j) {
    const int n = n0 + wn*64 + j*16 + lr;
    const float bvv = bias ? bias[(long long)z*biasBS + n] : 0.f;
    #pragma unroll
    for (int i=0;i<4;++i) {
      #pragma unroll
      for (int r=0;r<4;++r) {
        const int m = m0 + wm*64 + i*16 + lk*4 + r;
        float v = acc[i][j][r] + bvv;
        if (MODE == 0) {
          ((float*)Cv)[(long long)z*cBS + (long long)m*Ndim + n] = v;
        } else if (MODE == 1) {
          const int b_ = m >> 9, t_ = m & 511;
          ((float*)Cv)[(long long)z*cBS + ((long long)t_*2048 + n)*8 + b_] = v;
        } else if (MODE == 2) {
          const int b_ = m >> 9, t_ = m & 511;
          const int hd = n >> 7;
          ((float*)Cv)[(((long long)(b_*8 + hd))*512 + t_)*128 + (n & 127)] = v;
        } else if (MODE == 3) {
          float* cp = (float*)Cv + (long long)m*Ndim + n;
          *cp += v;
        } else if (MODE == 4) {
          ((u16*)Cv)[(long long)m*Ndim + n] = (u16)f2bf(gelu_f(v));
        }
      }
    }
  }
}

// ---------------- bf16x2 split (3-MFMA, ~fp32 accurate) GEMM ----------------
template<int MODE>
__global__ __launch_bounds__(256)
void k_b3gemm(const u16* __restrict__ Ah, const u16* __restrict__ Al,
              const u16* __restrict__ Bh, const u16* __restrict__ Bl,
              const float* __restrict__ bias, float* __restrict__ Cf,
              u16* __restrict__ Chi, u16* __restrict__ Clo,
              int Ndim, int Kdim)
{
  __shared__ __align__(16) u16 Ash[128*40];
  __shared__ __align__(16) u16 Asl[128*40];
  __shared__ __align__(16) u16 Bsh[128*40];
  __shared__ __align__(16) u16 Bsl[128*40];
  const int tid = threadIdx.x;
  const int m0 = blockIdx.y * 128, n0 = blockIdx.x * 128;
  const int wv = tid >> 6, l = tid & 63;
  const int wm = wv >> 1, wn = wv & 1;
  const int lr = l & 15, lk = l >> 4;
  const int str = tid >> 2, stc = (tid & 3)*8;
  f32x4 acc[4][4];
  #pragma unroll
  for (int i=0;i<4;++i)
    #pragma unroll
    for (int j=0;j<4;++j) acc[i][j] = (f32x4){0.f,0.f,0.f,0.f};

  for (int k0 = 0; k0 < Kdim; k0 += 32) {
    #pragma unroll
    for (int q = 0; q < 2; ++q) {
      const int r = q*64 + str;
      const long long ao = (long long)(m0 + r)*Kdim + k0 + stc;
      const long long bo = (long long)(n0 + r)*Kdim + k0 + stc;
      *(uint4*)&Ash[r*40 + stc] = *(const uint4*)&Ah[ao];
      *(uint4*)&Asl[r*40 + stc] = *(const uint4*)&Al[ao];
      *(uint4*)&Bsh[r*40 + stc] = *(const uint4*)&Bh[bo];
      *(uint4*)&Bsl[r*40 + stc] = *(const uint4*)&Bl[bo];
    }
    __syncthreads();
    bf16x8 ah[4], al_[4], bh[4], bl_[4];
    #pragma unroll
    for (int i=0;i<4;++i) {
      ah[i]  = *(bf16x8*)&Ash[(wm*64 + i*16 + lr)*40 + lk*8];
      al_[i] = *(bf16x8*)&Asl[(wm*64 + i*16 + lr)*40 + lk*8];
    }
    #pragma unroll
    for (int j=0;j<4;++j) {
      bh[j]  = *(bf16x8*)&Bsh[(wn*64 + j*16 + lr)*40 + lk*8];
      bl_[j] = *(bf16x8*)&Bsl[(wn*64 + j*16 + lr)*40 + lk*8];
    }
    #pragma unroll
    for (int i=0;i<4;++i)
      #pragma unroll
      for (int j=0;j<4;++j) {
        acc[i][j] = __builtin_amdgcn_mfma_f32_16x16x32_bf16(ah[i],  bh[j],  acc[i][j], 0, 0, 0);
        acc[i][j] = __builtin_amdgcn_mfma_f32_16x16x32_bf16(ah[i],  bl_[j], acc[i][j], 0, 0, 0);
        acc[i][j] = __builtin_amdgcn_mfma_f32_16x16x32_bf16(al_[i], bh[j],  acc[i][j], 0, 0, 0);
      }
    __syncthreads();
  }

  #pragma unroll
  for (int j=0;j<4;++j) {
    const int n = n0 + wn*64 + j*16 + lr;
    const float bvv = bias ? bias[n] : 0.f;
    #pragma unroll
    for (int i=0;i<4;++i) {
      #pragma unroll
      for (int r=0;r<4;++r) {
        const int m = m0 + wm*64 + i*16 + lk*4 + r;
        float v = acc[i][j][r] + bvv;
        if (MODE == 0) {
          Cf[(long long)m*Ndim + n] = v;
        } else if (MODE == 2) {
          const int b_ = m >> 9, t_ = m & 511;
          const int hd = n >> 7;
          const long long off = (((long long)(b_*8 + hd))*512 + t_)*128 + (n & 127);
          Cf[off] = v;
          const unsigned h = f2bf(v);
          Chi[off] = (u16)h;
          Clo[off] = (u16)f2bf(v - bf2f(h));
        }
      }
    }
  }
}

// ---------------- generic tiled fp32 GEMM (ctx / o) ----------------
template<int BT, int MODE>
__global__ __launch_bounds__(256)
void k_gemm(const float* __restrict__ A, const float* __restrict__ Bw,
            const float* __restrict__ bias, float* __restrict__ C,
            int Mdim, int Ndim, int Kdim,
            long long aBS, long long bBS, long long cBS, long long biasBS,
            const float* __restrict__ aux)
{
  __shared__ float As[16][128];
  __shared__ float Bs[16][128];
  const int tid = threadIdx.x;
  const int tx = tid & 15, ty = tid >> 4;
  const int m0 = blockIdx.y * 128, n0 = blockIdx.x * 128;
  const int z = blockIdx.z;
  const float* Ab = A + (long long)z * aBS;
  const float* Bb = Bw + (long long)z * bBS;
  float acc[8][8] = {};

  for (int k0 = 0; k0 < Kdim; k0 += 16) {
    #pragma unroll
    for (int l0 = 0; l0 < 512; l0 += 256) {
      const int ll = l0 + tid;
      const int r = ll >> 2, kq = (ll & 3) * 4;
      float4 v = *(const float4*)&Ab[(long long)(m0 + r) * Kdim + k0 + kq];
      As[kq+0][r] = v.x; As[kq+1][r] = v.y; As[kq+2][r] = v.z; As[kq+3][r] = v.w;
    }
    if (BT) {
      #pragma unroll
      for (int l0 = 0; l0 < 512; l0 += 256) {
        const int ll = l0 + tid;
        const int r = ll >> 2, kq = (ll & 3) * 4;
        float4 v = *(const float4*)&Bb[(long long)(n0 + r) * Kdim + k0 + kq];
        Bs[kq+0][r] = v.x; Bs[kq+1][r] = v.y; Bs[kq+2][r] = v.z; Bs[kq+3][r] = v.w;
      }
    } else {
      #pragma unroll
      for (int l0 = 0; l0 < 512; l0 += 256) {
        const int ll = l0 + tid;
        const int kr = ll >> 5, n4 = (ll & 31) * 4;
        *(float4*)&Bs[kr][n4] = *(const float4*)&Bb[(long long)(k0 + kr) * Ndim + n0 + n4];
      }
    }
    __syncthreads();
    #pragma unroll
    for (int kk = 0; kk < 16; ++kk) {
      float4 af0 = *(const float4*)&As[kk][ty*4];
      float4 af1 = *(const float4*)&As[kk][64 + ty*4];
      float4 bf0 = *(const float4*)&Bs[kk][tx*4];
      float4 bf1 = *(const float4*)&Bs[kk][64 + tx*4];
      float av[8] = {af0.x,af0.y,af0.z,af0.w,af1.x,af1.y,af1.z,af1.w};
      float bv[8] = {bf0.x,bf0.y,bf0.z,bf0.w,bf1.x,bf1.y,bf1.z,bf1.w};
      #pragma unroll
      for (int i = 0; i < 8; ++i)
        #pragma unroll
        for (int j = 0; j < 8; ++j)
          acc[i][j] = fmaf(av[i], bv[j], acc[i][j]);
    }
    __syncthreads();
  }

  float* Cz = C + (long long)z * cBS;
  #pragma unroll
  for (int i = 0; i < 8; ++i) {
    const int m = m0 + ((i < 4) ? (ty*4 + i) : (64 + ty*4 + (i - 4)));
    #pragma unroll
    for (int jb = 0; jb < 2; ++jb) {
      const int ci = n0 + (jb ? 64 : 0) + tx*4;
      float4 v;
      v.x = acc[i][jb*4+0]; v.y = acc[i][jb*4+1];
      v.z = acc[i][jb*4+2]; v.w = acc[i][jb*4+3];
      if (MODE == 0) {
        *(float4*)&Cz[(long long)m * Ndim + ci] = v;
      } else if (MODE == 5) {
        const int b_ = z >> 3, hd = z & 7;
        const float sc = aux[(long long)z*512 + m];
        u16* Cb = (u16*)C;
        const long long off = ((long long)(b_*512 + m))*1024 + hd*128 + ci;
        Cb[off+0] = (u16)f2bf(v.x*sc);
        Cb[off+1] = (u16)f2bf(v.y*sc);
        Cb[off+2] = (u16)f2bf(v.z*sc);
        Cb[off+3] = (u16)f2bf(v.w*sc);
      }
    }
  }
}

// ---------------- persistent BiLSTM recurrence v5 (tag-embedded sync) ----------
// grid = 32 WGs: blockIdx = dir*16 + slice. Each WG owns 32 hidden units.
// No flags: each 16B h-chunk carries a 3-bit step tag ((s%7)+1, never 0) stolen
// from the LSBs of bf16 elements 0..2. Consumers spin-load their chunk until the
// tag matches -> gather IS the barrier (one L3 RT per step instead of two).
// Race-free: WG drift <= 1 step, so a chunk holds h_s or h_{s-2} (tags differ,
// 2 != 0 mod 7). Cross-replay leftovers (h_510 tag 7, h_511 tag 1) mismatch the
// first reads (tags 3, 4); 0xAA poison gives tag 0 (never valid).
template<int OBF>
__global__ __launch_bounds__(512)
void k_lstm5(const float* __restrict__ Z, const float* __restrict__ Whh,
             float* __restrict__ outf, u16* __restrict__ outb,
             unsigned* __restrict__ hbufU)
{
  extern __shared__ char smem[];
  short*          Wl    = (short*)smem;              // 128*512 bf16 = 131072 B
  short*          hl    = (short*)(smem + 131072);   // 8*512 bf16  = 8192 B
  float*          gates = (float*)(smem + 139264);   // 128*8 f32   = 4096 B
  unsigned short* houts = (unsigned short*)(smem + 143360); // 8*32 u16 = 512 B

  const int slice = blockIdx.x & 15, dir = blockIdx.x >> 4;
  const int tid = threadIdx.x;
  const int u0 = slice * 32;

  // stage Whh slice -> LDS bf16 (8-elem blocks rotated by row)
  for (int blk = tid; blk < 8192; blk += 512) {
    const int lr2 = blk >> 6, bi = blk & 63;
    const long long src = ((long long)dir*2048 + (lr2>>5)*512 + u0 + (lr2&31))*512 + bi*8;
    float4 w0 = *(const float4*)&Whh[src];
    float4 w1 = *(const float4*)&Whh[src + 4];
    unsigned* dst = (unsigned*)&Wl[lr2*512 + (((bi + lr2) & 63) << 3)];
    dst[0] = f2bf(w0.x) | (f2bf(w0.y) << 16);
    dst[1] = f2bf(w0.z) | (f2bf(w0.w) << 16);
    dst[2] = f2bf(w1.x) | (f2bf(w1.y) << 16);
    dst[3] = f2bf(w1.z) | (f2bf(w1.w) << 16);
  }
  for (int i = tid; i < 2048; i += 512) ((unsigned*)hl)[i] = 0u;

  const int wv = tid >> 6, l = tid & 63;
  const int arow = wv*16 + (l & 15);
  const int bb   = l & 7;
  const int qoff = l >> 4;
  const int jj = tid >> 3, bcomb = tid & 7;
  float cst = 0.f;
  int gt = 1;   // gather tag at step s: (s%7)+1
  int pt = 2;   // publish tag for h_{s+1}: ((s+1)%7)+1

  for (int s = 0; s < 512; ++s) {
    const int t = dir ? (511 - s) : s;
    // early-issue Z loads (fp32, layout [dir][t][row][b]); coalesced
    float z0v = 0.f, z1v = 0.f, z2v = 0.f, z3v = 0.f;
    if (tid < 256) {
      const float* zp = Z + (((long long)dir*512 + t)*16384) + (u0 + jj)*8 + bcomb;
      z0v = zp[0]; z1v = zp[4096]; z2v = zp[8192]; z3v = zp[12288];
    }
    if (s > 0) {
      // gather+sync fused: spin on own 16B chunk until its embedded tag matches
      const unsigned base = ((unsigned)((s & 1)*2 + dir)) * 2048;
      const unsigned* src = &hbufU[base + tid*4];
      u32x4 v;
      for (;;) {
        v = ld16_sc1(src);
        const int tag = (int)((v.x & 1u) | (((v.x >> 16) & 1u) << 1) | ((v.y & 1u) << 2));
        if (tag == gt) break;
      }
      const int b = tid >> 6, q = tid & 63;
      *(u32x4*)((char*)hl + b*1024 + (((q + b) & 63) << 4)) = v;
    }
    __syncthreads();
    // gates = W @ h via mfma (two independent chains)
    f32x4 acc0 = {0.f,0.f,0.f,0.f}, acc1 = {0.f,0.f,0.f,0.f};
    #pragma unroll
    for (int ks = 0; ks < 8; ++ks) {
      const int qa = (2*ks)*4 + qoff, qb = (2*ks + 1)*4 + qoff;
      bf16x8 a0 = *(bf16x8*)&Wl[arow*512 + (((qa + arow) & 63) << 3)];
      bf16x8 b0 = *(bf16x8*)&hl[bb*512   + (((qa + bb)   & 63) << 3)];
      acc0 = __builtin_amdgcn_mfma_f32_16x16x32_bf16(a0, b0, acc0, 0, 0, 0);
      bf16x8 a1 = *(bf16x8*)&Wl[arow*512 + (((qb + arow) & 63) << 3)];
      bf16x8 b1 = *(bf16x8*)&hl[bb*512   + (((qb + bb)   & 63) << 3)];
      acc1 = __builtin_amdgcn_mfma_f32_16x16x32_bf16(a1, b1, acc1, 0, 0, 0);
    }
    const int bcol = l & 15;
    if (bcol < 8) {
      #pragma unroll
      for (int r = 0; r < 4; ++r)
        gates[(wv*16 + qoff*4 + r)*8 + bcol] = acc0[r] + acc1[r];
    }
    __syncthreads();
    if (tid < 256) {
      const float gi = gates[jj*8        + bcomb] + z0v;
      const float gf = gates[(32+jj)*8   + bcomb] + z1v;
      const float gg = gates[(64+jj)*8   + bcomb] + z2v;
      const float go = gates[(96+jj)*8   + bcomb] + z3v;
      const float ig = 1.f/(1.f + expf(-gi));
      const float fg = 1.f/(1.f + expf(-gf));
      const float og = 1.f/(1.f + expf(-go));
      cst = fg*cst + ig*tanhf(gg);
      const float hv = og*tanhf(cst);
      const unsigned hb = f2bf(hv);
      if (OBF) outb[((long long)(bcomb*512 + t))*1024 + (dir<<9) + u0 + jj] = (u16)hb;
      else     outf[((long long)(bcomb*512 + t))*1024 + (dir<<9) + u0 + jj] = hv;
      houts[bcomb*32 + jj] = (unsigned short)hb;
    }
    __syncthreads();
    if (s != 511 && tid < 32) {
      // publish: 32 threads x 16B sc1 stores, tag in LSBs of bf16 elems 0..2
      const int b = tid >> 2, q4 = tid & 3;
      u32x4 w = *(const u32x4*)&houts[b*32 + q4*8];
      w.x = (w.x & ~0x00010001u) | (unsigned)(pt & 1) | (((unsigned)(pt >> 1) & 1u) << 16);
      w.y = (w.y & ~1u) | ((unsigned)(pt >> 2) & 1u);
      const unsigned base2 = ((unsigned)(((s+1) & 1)*2 + dir)) * 2048;
      st16_sc1(&hbufU[base2 + b*256 + (u0 >> 1) + q4*4], w);
    }
    gt = (gt == 7) ? 1 : gt + 1;
    pt = (pt == 7) ? 1 : pt + 1;
  }
}

// ---------------- LayerNorm: fp32 in, bf16 hi+lo out ----------------
__global__ __launch_bounds__(256)
void k_ln(const float* __restrict__ X, const float* __restrict__ gw,
          const float* __restrict__ bw, u16* __restrict__ Yh, u16* __restrict__ Yl)
{
  const int row = blockIdx.x, tid = threadIdx.x;
  const float* xr = X + (long long)row * 1024;
  float4 v = *(const float4*)&xr[tid*4];
  float s  = v.x + v.y + v.z + v.w;
  float ss = v.x*v.x + v.y*v.y + v.z*v.z + v.w*v.w;
  #pragma unroll
  for (int off = 1; off < 64; off <<= 1) {
    s  += __shfl_xor(s, off, 64);
    ss += __shfl_xor(ss, off, 64);
  }
  __shared__ float rs[4], rss[4];
  const int w = tid >> 6;
  if ((tid & 63) == 0) { rs[w] = s; rss[w] = ss; }
  __syncthreads();
  s  = rs[0] + rs[1] + rs[2] + rs[3];
  ss = rss[0] + rss[1] + rss[2] + rss[3];
  const float mu = s * (1.f/1024.f);
  const float var = ss * (1.f/1024.f) - mu*mu;
  const float rstd = rsqrtf(var + 1e-5f);
  float4 g4 = *(const float4*)&gw[tid*4];
  float4 b4 = *(const float4*)&bw[tid*4];
  float4 o;
  o.x = (v.x - mu)*rstd*g4.x + b4.x;
  o.y = (v.y - mu)*rstd*g4.y + b4.y;
  o.z = (v.z - mu)*rstd*g4.z + b4.z;
  o.w = (v.w - mu)*rstd*g4.w + b4.w;
  ushort4 hh, ll;
  hh.x=(u16)f2bf(o.x); ll.x=(u16)f2bf(o.x - bf2f(f2bf(o.x)));
  hh.y=(u16)f2bf(o.y); ll.y=(u16)f2bf(o.y - bf2f(f2bf(o.y)));
  hh.z=(u16)f2bf(o.z); ll.z=(u16)f2bf(o.z - bf2f(f2bf(o.z)));
  hh.w=(u16)f2bf(o.w); ll.w=(u16)f2bf(o.w - bf2f(f2bf(o.w)));
  *(ushort4*)&Yh[(long long)row*1024 + tid*4] = hh;
  *(ushort4*)&Yl[(long long)row*1024 + tid*4] = ll;
}

// ---------------- FAVOR helpers ----------------
__global__ void k_diag(const float* __restrict__ X, float* __restrict__ dout)
{
  const int tid = threadIdx.x;
  const int row = blockIdx.x*4 + (tid >> 6);
  const int lane = tid & 63;
  float2 v = *(const float2*)&X[(long long)row*128 + lane*2];
  float ss = v.x*v.x + v.y*v.y;
  #pragma unroll
  for (int off = 1; off < 64; off <<= 1) ss += __shfl_xor(ss, off, 64);
  if (lane == 0) dout[row] = ss * 0.044194173824159216f; // 0.5 * dn^2
}

__global__ void k_favq(float* __restrict__ dd, const float* __restrict__ diag)
{
  const int tid = threadIdx.x;
  const int row = blockIdx.x*4 + (tid >> 6);
  const int lane = tid & 63;
  float4 v = *(const float4*)&dd[(long long)row*256 + lane*4];
  float mx = fmaxf(fmaxf(v.x, v.y), fmaxf(v.z, v.w));
  #pragma unroll
  for (int off = 1; off < 64; off <<= 1) mx = fmaxf(mx, __shfl_xor(mx, off, 64));
  const float dg = diag[row];
  float4 o;
  o.x = (expf(v.x - dg - mx) + KEPS)*0.0625f;
  o.y = (expf(v.y - dg - mx) + KEPS)*0.0625f;
  o.z = (expf(v.z - dg - mx) + KEPS)*0.0625f;
  o.w = (expf(v.w - dg - mx) + KEPS)*0.0625f;
  *(float4*)&dd[(long long)row*256 + lane*4] = o;
}

__global__ __launch_bounds__(256)
void k_kmax(const float* __restrict__ dd, float* __restrict__ kmx)
{
  const int bh = blockIdx.x, tid = threadIdx.x;
  const float* p = dd + (long long)bh * 131072;
  float mx = -3.4e38f;
  for (int i = tid*4; i < 131072; i += 1024) {
    float4 v = *(const float4*)&p[i];
    mx = fmaxf(mx, fmaxf(fmaxf(v.x, v.y), fmaxf(v.z, v.w)));
  }
  #pragma unroll
  for (int off = 1; off < 64; off <<= 1) mx = fmaxf(mx, __shfl_xor(mx, off, 64));
  __shared__ float red[4];
  if ((tid & 63) == 0) red[tid >> 6] = mx;
  __syncthreads();
  if (tid == 0) kmx[bh] = fmaxf(fmaxf(red[0], red[1]), fmaxf(red[2], red[3]));
}

__global__ void k_fkT(const float* __restrict__ dd, const float* __restrict__ diag,
                      const float* __restrict__ kmx, float* __restrict__ kT)
{
  __shared__ float tile[32][33];
  const int bh = blockIdx.z;
  const int t0 = blockIdx.x * 32, m0 = blockIdx.y * 32;
  const int tx = threadIdx.x, ty = threadIdx.y;
  const float km = kmx[bh];
  #pragma unroll
  for (int j = 0; j < 4; ++j) {
    const int t = t0 + ty + j*8;
    const float v = dd[((long long)bh*512 + t)*256 + m0 + tx];
    tile[ty + j*8][tx] = (expf(v - diag[bh*512 + t] - km) + KEPS) * 0.0625f;
  }
  __syncthreads();
  #pragma unroll
  for (int j = 0; j < 4; ++j) {
    const int m = m0 + ty + j*8;
    kT[((long long)bh*256 + m)*512 + t0 + tx] = tile[tx][ty + j*8];
  }
}

__global__ void k_ksum(const float* __restrict__ kT, float* __restrict__ ksum)
{
  const int tid = threadIdx.x;
  const int row = blockIdx.x*4 + (tid >> 6);
  const int lane = tid & 63;
  float4 a = *(const float4*)&kT[(long long)row*512 + lane*8];
  float4 b = *(const float4*)&kT[(long long)row*512 + lane*8 + 4];
  float s = a.x+a.y+a.z+a.w + b.x+b.y+b.z+b.w;
  #pragma unroll
  for (int off = 1; off < 64; off <<= 1) s += __shfl_xor(s, off, 64);
  if (lane == 0) ksum[row] = s;
}

__global__ void k_dinv(const float* __restrict__ qp, const float* __restrict__ ksum,
                       float* __restrict__ dinv)
{
  const int tid = threadIdx.x;
  const int row = blockIdx.x*4 + (tid >> 6);
  const int lane = tid & 63;
  const int bh = row >> 9;
  float4 q = *(const float4*)&qp[(long long)row*256 + lane*4];
  float4 k = *(const float4*)&ksum[bh*256 + lane*4];
  float s = q.x*k.x + q.y*k.y + q.z*k.z + q.w*k.w;
  #pragma unroll
  for (int off = 1; off < 64; off <<= 1) s += __shfl_xor(s, off, 64);
  if (lane == 0) dinv[row] = 1.f / s;
}

// ---------------- pooling + classifier ----------------
__global__ void k_pool(const float* __restrict__ h, float* __restrict__ pooled)
{
  const int idx = blockIdx.x * 256 + threadIdx.x; // 8192
  const int b = idx >> 10, d = idx & 1023;
  const float* p = h + (long long)b * 524288 + d;
  float s0=0,s1=0,s2=0,s3=0;
  for (int t0 = 0; t0 < 512; t0 += 4) {
    s0 += p[(long long)(t0+0)*1024];
    s1 += p[(long long)(t0+1)*1024];
    s2 += p[(long long)(t0+2)*1024];
    s3 += p[(long long)(t0+3)*1024];
  }
  pooled[idx] = (s0+s1+s2+s3) * (1.f/512.f);
}

__global__ __launch_bounds__(256)
void k_cls(const float* __restrict__ pooled, const float* __restrict__ W1,
           const float* __restrict__ b1, const float* __restrict__ W2,
           const float* __restrict__ b2, float* __restrict__ out)
{
  const int b = blockIdx.x, tid = threadIdx.x;
  __shared__ float pl[1024];
  __shared__ float hd[512];
  *(float4*)&pl[tid*4] = *(const float4*)&pooled[b*1024 + tid*4];
  __syncthreads();
  for (int u = tid; u < 512; u += 256) {
    float acc = b1[u];
    for (int k = 0; k < 1024; ++k) acc = fmaf(pl[k], W1[(long long)k*512 + u], acc);
    hd[u] = fmaxf(acc, 0.f);
  }
  __syncthreads();
  if (tid < 2) {
    float acc = b2[tid];
    for (int k = 0; k < 512; ++k) acc = fmaf(hd[k], W2[k*2 + tid], acc);
    out[b*2 + tid] = acc;
  }
}

// ---------------- host ----------------
static void* symp(const void* s) { void* p = nullptr; (void)hipGetSymbolAddress(&p, s); return p; }

extern "C" void kernel_launch(void* const* d_in, const int* in_sizes, int n_in,
                              void* d_out, int out_size, void* d_ws, size_t ws_size,
                              hipStream_t stream)
{
  (void)in_sizes; (void)n_in; (void)d_ws; (void)ws_size; (void)out_size;
  const float* x     = (const float*)d_in[0];
  const float* l0Wih = (const float*)d_in[1];
  const float* l0Whh = (const float*)d_in[2];
  const float* l0bih = (const float*)d_in[3];
  const float* l0bhh = (const float*)d_in[4];
  const float* l1Wih = (const float*)d_in[5];
  const float* l1Whh = (const float*)d_in[6];
  const float* l1bih = (const float*)d_in[7];
  const float* l1bhh = (const float*)d_in[8];
  const float* proj  = (const float*)d_in[9];
  const float* ln1g  = (const float*)d_in[10];
  const float* ln1b  = (const float*)d_in[11];
  const float* Wq    = (const float*)d_in[12];
  const float* Wk    = (const float*)d_in[13];
  const float* Wv    = (const float*)d_in[14];
  const float* Wo    = (const float*)d_in[15];
  const float* bq    = (const float*)d_in[16];
  const float* bk    = (const float*)d_in[17];
  const float* bv    = (const float*)d_in[18];
  const float* bo    = (const float*)d_in[19];
  const float* ln2g  = (const float*)d_in[20];
  const float* ln2b  = (const float*)d_in[21];
  const float* Wf1   = (const float*)d_in[22];
  const float* bf1   = (const float*)d_in[23];
  const float* Wf2   = (const float*)d_in[24];
  const float* bf2   = (const float*)d_in[25];
  const float* cW1   = (const float*)d_in[26];
  const float* cb1   = (const float*)d_in[27];
  const float* cW2   = (const float*)d_in[28];
  const float* cb2   = (const float*)d_in[29];

  float* z0    = (float*)symp(HIP_SYMBOL(g_z0));
  float* z1    = (float*)symp(HIP_SYMBOL(g_z1));
  float* hres  = (float*)symp(HIP_SYMBOL(g_hres));
  float* qlin  = (float*)symp(HIP_SYMBOL(g_qlin));
  float* klin  = (float*)symp(HIP_SYMBOL(g_klin));
  float* vlin  = (float*)symp(HIP_SYMBOL(g_vlin));
  float* qp    = (float*)symp(HIP_SYMBOL(g_qp));
  float* ddb   = (float*)symp(HIP_SYMBOL(g_ddb));
  float* kT    = (float*)symp(HIP_SYMBOL(g_kT));
  float* ctx   = (float*)symp(HIP_SYMBOL(g_ctx));
  float* bs0   = (float*)symp(HIP_SYMBOL(g_bs0));
  float* bs1   = (float*)symp(HIP_SYMBOL(g_bs1));
  float* diagq = (float*)symp(HIP_SYMBOL(g_diagq));
  float* diagk = (float*)symp(HIP_SYMBOL(g_diagk));
  float* kmx   = (float*)symp(HIP_SYMBOL(g_kmx));
  float* ksum  = (float*)symp(HIP_SYMBOL(g_ksum));
  float* dinv  = (float*)symp(HIP_SYMBOL(g_dinv));
  unsigned* hbuf = (unsigned*)symp(HIP_SYMBOL(g_hbuf));
  float* pooled= (float*)symp(HIP_SYMBOL(g_pooled));
  u16* xbf   = (u16*)symp(HIP_SYMBOL(g_xbf));
  u16* x1bf  = (u16*)symp(HIP_SYMBOL(g_x1bf));
  u16* ybf   = (u16*)symp(HIP_SYMBOL(g_ybf));
  u16* ylo   = (u16*)symp(HIP_SYMBOL(g_ylo));
  u16* obufbf= (u16*)symp(HIP_SYMBOL(g_obufbf));
  u16* ffbbf = (u16*)symp(HIP_SYMBOL(g_ffbbf));
  u16* qhi   = (u16*)symp(HIP_SYMBOL(g_qhi));
  u16* qlo2  = (u16*)symp(HIP_SYMBOL(g_qlo2));
  u16* khi   = (u16*)symp(HIP_SYMBOL(g_khi));
  u16* klo2  = (u16*)symp(HIP_SYMBOL(g_klo2));
  u16* wih0b = (u16*)symp(HIP_SYMBOL(g_wih0b));
  u16* wih1b = (u16*)symp(HIP_SYMBOL(g_wih1b));
  u16* wvt   = (u16*)symp(HIP_SYMBOL(g_wvt));
  u16* wot   = (u16*)symp(HIP_SYMBOL(g_wot));
  u16* wf1t  = (u16*)symp(HIP_SYMBOL(g_wf1t));
  u16* wf2t  = (u16*)symp(HIP_SYMBOL(g_wf2t));
  u16* wqth  = (u16*)symp(HIP_SYMBOL(g_wqth));
  u16* wqtl  = (u16*)symp(HIP_SYMBOL(g_wqtl));
  u16* wkth  = (u16*)symp(HIP_SYMBOL(g_wkth));
  u16* wktl  = (u16*)symp(HIP_SYMBOL(g_wktl));
  u16* projh = (u16*)symp(HIP_SYMBOL(g_projh));
  u16* projl = (u16*)symp(HIP_SYMBOL(g_projl));

  const float dn = 0.29730177875068026f; // 128^-0.25
  const int LSTM_LDS = 143872;
  (void)hipFuncSetAttribute((const void*)k_lstm5<1>,
                            hipFuncAttributeMaxDynamicSharedMemorySize, LSTM_LDS);
  (void)hipFuncSetAttribute((const void*)k_lstm5<0>,
                            hipFuncAttributeMaxDynamicSharedMemorySize, LSTM_LDS);

  k_add2<<<16, 256, 0, stream>>>(bs0, l0bih, l0bhh, 4096);
  k_add2<<<16, 256, 0, stream>>>(bs1, l1bih, l1bhh, 4096);
  k_scale_split<<<128, 256, 0, stream>>>(proj, projh, projl, dn, 32768);

  // convert inputs/weights to bf16
  k_cvt<<<1024, 256, 0, stream>>>(x, xbf, 262144);
  k_cvt<<<1024, 256, 0, stream>>>(l0Wih, wih0b, 262144);
  k_cvt<<<4096, 256, 0, stream>>>(l1Wih, wih1b, 1048576);
  k_w2bfT<<<dim3(32,32,2),  dim3(32,8), 0, stream>>>(Wv,  wvt,  1024, 1024, 1048576LL, 1048576LL);
  k_w2bfT<<<dim3(32,32,2),  dim3(32,8), 0, stream>>>(Wo,  wot,  1024, 1024, 1048576LL, 1048576LL);
  k_w2bfT<<<dim3(128,32,2), dim3(32,8), 0, stream>>>(Wf1, wf1t, 1024, 4096, 4194304LL, 4194304LL);
  k_w2bfT<<<dim3(32,128,2), dim3(32,8), 0, stream>>>(Wf2, wf2t, 4096, 1024, 4194304LL, 4194304LL);
  k_w2bfT_split<<<dim3(32,32,2), dim3(32,8), 0, stream>>>(Wq, wqth, wqtl, 1024, 1024, 1048576LL, 1048576LL);
  k_w2bfT_split<<<dim3(32,32,2), dim3(32,8), 0, stream>>>(Wk, wkth, wktl, 1024, 1024, 1048576LL, 1048576LL);

  // LSTM layer 0
  k_bgemm<1><<<dim3(16,32,2), 256, 0, stream>>>(xbf, wih0b, bs0, z0,
      2048, 256, 0LL, 524288LL, 8388608LL, 2048LL);
  k_lstm5<1><<<32, 512, LSTM_LDS, stream>>>(z0, l0Whh, nullptr, x1bf, hbuf);
  // LSTM layer 1
  k_bgemm<1><<<dim3(16,32,2), 256, 0, stream>>>(x1bf, wih1b, bs1, z1,
      2048, 1024, 0LL, 2097152LL, 8388608LL, 2048LL);
  k_lstm5<0><<<32, 512, LSTM_LDS, stream>>>(z1, l1Whh, hres, nullptr, hbuf);

  for (int i = 0; i < 2; ++i) {
    const long long wOffU = (long long)i * 1048576;
    // pre-norm attention
    k_ln<<<4096, 256, 0, stream>>>(hres, ln1g + i*1024, ln1b + i*1024, ybf, ylo);
    k_b3gemm<2><<<dim3(8,32,1), 256, 0, stream>>>(ybf, ylo, wqth + wOffU, wqtl + wOffU,
        bq + i*1024, qlin, qhi, qlo2, 1024, 1024);
    k_b3gemm<2><<<dim3(8,32,1), 256, 0, stream>>>(ybf, ylo, wkth + wOffU, wktl + wOffU,
        bk + i*1024, klin, khi, klo2, 1024, 1024);
    k_bgemm<2><<<dim3(8,32,1), 256, 0, stream>>>(ybf, wvt + wOffU, bv + i*1024, vlin,
        1024, 1024, 0LL, 0LL, 0LL, 0LL);
    k_diag<<<8192, 256, 0, stream>>>(qlin, diagq);
    k_diag<<<8192, 256, 0, stream>>>(klin, diagk);
    // FAVOR q
    k_b3gemm<0><<<dim3(2,256,1), 256, 0, stream>>>(qhi, qlo2, projh, projl,
        nullptr, qp, nullptr, nullptr, 256, 128);
    k_favq<<<8192, 256, 0, stream>>>(qp, diagq);
    // FAVOR k
    k_b3gemm<0><<<dim3(2,256,1), 256, 0, stream>>>(khi, klo2, projh, projl,
        nullptr, ddb, nullptr, nullptr, 256, 128);
    k_kmax<<<64, 256, 0, stream>>>(ddb, kmx);
    k_fkT<<<dim3(16,8,64), dim3(32,8), 0, stream>>>(ddb, diagk, kmx, kT);
    k_ksum<<<4096, 256, 0, stream>>>(kT, ksum);
    // ctx = k'^T @ v
    k_gemm<0,0><<<dim3(1,2,64), 256, 0, stream>>>(kT, vlin, nullptr, ctx,
        256, 128, 512, 131072LL, 65536LL, 32768LL, 0LL, nullptr);
    k_dinv<<<8192, 256, 0, stream>>>(qp, ksum, dinv);
    // o = (q' @ ctx) * dinv -> bf16 merged heads
    k_gemm<0,5><<<dim3(1,4,64), 256, 0, stream>>>(qp, ctx, nullptr, (float*)obufbf,
        512, 128, 256, 131072LL, 32768LL, 0LL, 0LL, dinv);
    // output projection + residual
    k_bgemm<3><<<dim3(8,32,1), 256, 0, stream>>>(obufbf, wot + wOffU, bo + i*1024, hres,
        1024, 1024, 0LL, 0LL, 0LL, 0LL);
    // pre-norm FF
    k_ln<<<4096, 256, 0, stream>>>(hres, ln2g + i*1024, ln2b + i*1024, ybf, ylo);
    k_bgemm<4><<<dim3(32,32,1), 256, 0, stream>>>(ybf, wf1t + (long long)i*4194304,
        bf1 + i*4096, ffbbf, 4096, 1024, 0LL, 0LL, 0LL, 0LL);
    k_bgemm<3><<<dim3(8,32,1), 256, 0, stream>>>(ffbbf, wf2t + (long long)i*4194304,
        bf2 + i*1024, hres, 1024, 4096, 0LL, 0LL, 0LL, 0LL);
  }

  k_pool<<<32, 256, 0, stream>>>(hres, pooled);
  k_cls<<<8, 256, 0, stream>>>(pooled, cW1, cb1, cW2, cb2, (float*)d_out);
}